// Round 3
// baseline (712.032 us; speedup 1.0000x reference)
//
#include <hip/hip_runtime.h>

#define N 2048
#define D 128
#define BB 16

typedef __attribute__((ext_vector_type(8))) short s16x8;   // 8 bf16 = 4 VGPR
typedef __attribute__((ext_vector_type(4))) float f32x4;   // MFMA acc

// Split two fp32 into packed bf16 hi (h) and bf16 lo (l) words.
// hi = truncate-to-bf16(x); lo = truncate-to-bf16(x - hi).  ~2^-16 rel total.
__device__ __forceinline__ void split2(float x0, float x1, unsigned& h, unsigned& l) {
    unsigned b0 = __float_as_uint(x0), b1 = __float_as_uint(x1);
    float r0 = x0 - __uint_as_float(b0 & 0xffff0000u);
    float r1 = x1 - __uint_as_float(b1 & 0xffff0000u);
    h = (b0 >> 16) | (b1 & 0xffff0000u);
    l = (__float_as_uint(r0) >> 16) | (__float_as_uint(r1) & 0xffff0000u);
}

// ---------------------------------------------------------------------------
// Kernel 0: zero the `out` region (rowsum accumulators live at out[b][i][0]).
// ---------------------------------------------------------------------------
__global__ __launch_bounds__(256) void zero_kernel(float4* __restrict__ p, int n4) {
    int i = blockIdx.x * 256 + threadIdx.x;
    const int stride = gridDim.x * 256;
    for (; i < n4; i += stride) p[i] = make_float4(0.f, 0.f, 0.f, 0.f);
}

// ---------------------------------------------------------------------------
// Kernel V: pre-transpose + hi/lo split of V into workspace:
//   Vt_h/Vt_l [b][d=128][n=2048] bf16.
// Each lane gathers an 8-element column of V via 8 coalesced row reads
// (wave reads V[n0+i][d0..d0+63], 256B segments), packs, writes 16B.
// No LDS, no conflicts. ~10 us total.
// ---------------------------------------------------------------------------
__global__ __launch_bounds__(256) void vt_kernel(const float* __restrict__ v,
                                                 unsigned short* __restrict__ vth,
                                                 unsigned short* __restrict__ vtl) {
    const int t    = threadIdx.x;
    const int lane = t & 63;
    const int w    = t >> 6;
    const int b    = blockIdx.z;
    const int n0   = blockIdx.x * 32 + w * 8;
    const int d    = blockIdx.y * 64 + lane;
    const float* vp = v + ((size_t)b * N + n0) * D + d;
    float x[8];
    #pragma unroll
    for (int i = 0; i < 8; ++i) x[i] = vp[(size_t)i * D];
    uint4 h, l;
    split2(x[0], x[1], h.x, l.x);
    split2(x[2], x[3], h.y, l.y);
    split2(x[4], x[5], h.z, l.z);
    split2(x[6], x[7], h.w, l.w);
    size_t idx = ((size_t)b * D + d) * N + n0;
    *(uint4*)(vth + idx) = h;
    *(uint4*)(vtl + idx) = l;
}

// ---------------------------------------------------------------------------
// Kernel 1: E = exp(Q @ K^T) via bf16 hi/lo MFMA (3-term), 128x128 tile,
// 4 waves. Also atomically accumulates row sums of E into out[b][i][0].
// LDS: per-K-step (BK=32) hi/lo tiles of Q and K, 16B-granule XOR swizzle.
// ---------------------------------------------------------------------------
__global__ __launch_bounds__(256) void qk_kernel(const float* __restrict__ q,
                                                 const float* __restrict__ k,
                                                 float* __restrict__ attn,
                                                 float* __restrict__ outp) {
    __shared__ unsigned short Qh[128 * 32], Ql[128 * 32];
    __shared__ unsigned short Kh[128 * 32], Kl[128 * 32];
    const int t  = threadIdx.x;
    const int b  = blockIdx.z;
    const int ib = blockIdx.y * 128;
    const int jb = blockIdx.x * 128;
    const float* qp = q + ((size_t)b * N + ib) * D;
    const float* kp = k + ((size_t)b * N + jb) * D;

    const int lane = t & 63;
    const int w    = t >> 6;
    const int wr   = (w >> 1) * 64;   // wave row quadrant
    const int wc   = (w & 1) * 64;    // wave col quadrant
    const int l15  = lane & 15;
    const int l4   = lane >> 4;

    f32x4 acc[4][4] = {};

    for (int ks = 0; ks < 4; ++ks) {
        __syncthreads();
        // Stage Q/K [128 rows][32 k] fp32 -> hi/lo bf16 LDS (swizzled).
        #pragma unroll
        for (int c = 0; c < 4; ++c) {
            int flat = c * 256 + t;        // 1024 float4 per matrix
            int row  = flat >> 3;          // 8 float4 per row
            int f4   = flat & 7;
            float4 qv = *(const float4*)(qp + (size_t)row * D + ks * 32 + f4 * 4);
            float4 kv = *(const float4*)(kp + (size_t)row * D + ks * 32 + f4 * 4);
            int idx = row * 32 + (((f4 >> 1) ^ (row & 3)) * 8) + (f4 & 1) * 4;
            uint2 hh, ll;
            split2(qv.x, qv.y, hh.x, ll.x);
            split2(qv.z, qv.w, hh.y, ll.y);
            *(uint2*)(Qh + idx) = hh;
            *(uint2*)(Ql + idx) = ll;
            split2(kv.x, kv.y, hh.x, ll.x);
            split2(kv.z, kv.w, hh.y, ll.y);
            *(uint2*)(Kh + idx) = hh;
            *(uint2*)(Kl + idx) = ll;
        }
        __syncthreads();

        // Fragments: A lane reads Q[row=l15][8*l4 .. +7], B reads K-row likewise.
        s16x8 ah[4], al[4], bh[4], bl[4];
        #pragma unroll
        for (int ti = 0; ti < 4; ++ti) {
            int row = wr + ti * 16 + l15;
            int idx = row * 32 + ((l4 ^ (row & 3)) * 8);
            ah[ti] = *(const s16x8*)(Qh + idx);
            al[ti] = *(const s16x8*)(Ql + idx);
        }
        #pragma unroll
        for (int tj = 0; tj < 4; ++tj) {
            int row = wc + tj * 16 + l15;
            int idx = row * 32 + ((l4 ^ (row & 3)) * 8);
            bh[tj] = *(const s16x8*)(Kh + idx);
            bl[tj] = *(const s16x8*)(Kl + idx);
        }
        #pragma unroll
        for (int ti = 0; ti < 4; ++ti)
            #pragma unroll
            for (int tj = 0; tj < 4; ++tj) {
                acc[ti][tj] = __builtin_amdgcn_mfma_f32_16x16x32_bf16(ah[ti], bh[tj], acc[ti][tj], 0, 0, 0);
                acc[ti][tj] = __builtin_amdgcn_mfma_f32_16x16x32_bf16(ah[ti], bl[tj], acc[ti][tj], 0, 0, 0);
                acc[ti][tj] = __builtin_amdgcn_mfma_f32_16x16x32_bf16(al[ti], bh[tj], acc[ti][tj], 0, 0, 0);
            }
    }

    // Epilogue: E = exp(s) (no max subtraction needed: |s| <= ~70 < 88),
    // store E, reduce row partial sums over this block's 128 cols, atomicAdd.
    #pragma unroll
    for (int ti = 0; ti < 4; ++ti) {
        #pragma unroll
        for (int r = 0; r < 4; ++r) {
            int row = ib + wr + ti * 16 + l4 * 4 + r;
            float* arow = attn + ((size_t)b * N + row) * N + jb + wc;
            float rs = 0.f;
            #pragma unroll
            for (int tj = 0; tj < 4; ++tj) {
                float e = __expf(acc[ti][tj][r]);
                arow[tj * 16 + l15] = e;
                rs += e;
            }
            rs += __shfl_xor(rs, 1);
            rs += __shfl_xor(rs, 2);
            rs += __shfl_xor(rs, 4);
            rs += __shfl_xor(rs, 8);
            if (l15 == 0) atomicAdd(outp + ((size_t)b * N + row) * D, rs);
        }
    }
}

// ---------------------------------------------------------------------------
// Kernel 2 (fast path): P = E * (1/rowsum) written in-place to attn;
// O = P @ V via bf16 hi/lo MFMA. V comes PRE-TRANSPOSED+SPLIT from ws
// (Vt_h/Vt_l [b][d][n]), so LDS staging is plain coalesced float4 copies
// into row-major [d][64] + XOR-granule swizzle — no transpose conflicts.
// ---------------------------------------------------------------------------
__global__ __launch_bounds__(256) void pv_pre_kernel(const unsigned short* __restrict__ vth,
                                                     const unsigned short* __restrict__ vtl,
                                                     float* __restrict__ attn,
                                                     float* __restrict__ outp) {
    __shared__ unsigned short Ph[64 * 64], Pl[64 * 64];
    __shared__ unsigned short Vh[128 * 64], Vl[128 * 64];
    __shared__ float invs[64];
    const int t  = threadIdx.x;
    const int b  = blockIdx.y;
    const int ib = blockIdx.x * 64;
    float* ap = attn + ((size_t)b * N + ib) * N;
    const unsigned short* vhp = vth + (size_t)b * D * N;
    const unsigned short* vlp = vtl + (size_t)b * D * N;
    float* op = outp + ((size_t)b * N + ib) * D;

    if (t < 64) invs[t] = 1.0f / op[(size_t)t * D];   // rowsum from QK atomics

    const int lane = t & 63;
    const int w    = t >> 6;
    const int rg   = (w >> 1) * 32;   // wave row group (32 rows)
    const int dg   = (w & 1) * 64;    // wave d group (64 cols)
    const int l15  = lane & 15;
    const int l4   = lane >> 4;

    f32x4 acc[2][4] = {};

    // Register prefetch: E (4x float4), Vt hi/lo (4+4 float4).
    float4 pe[4], fh[4], fl[4];
    #pragma unroll
    for (int c = 0; c < 4; ++c) {
        int flat = c * 256 + t;
        pe[c] = *(const float4*)(ap + (size_t)(flat >> 4) * N + (flat & 15) * 4);
        int d = flat >> 3, g = flat & 7;
        fh[c] = *(const float4*)(vhp + (size_t)d * N + g * 8);
        fl[c] = *(const float4*)(vlp + (size_t)d * N + g * 8);
    }

    for (int jc = 0; jc < 32; ++jc) {
        __syncthreads();   // LDS free (prev compute done); also fences invs on jc=0
        // Stage P: p = E*inv; write normalized attn in-place; hi/lo -> LDS.
        #pragma unroll
        for (int c = 0; c < 4; ++c) {
            int flat = c * 256 + t;
            int row = flat >> 4, j4 = flat & 15;
            float iv = invs[row];
            float4 p4;
            p4.x = pe[c].x * iv; p4.y = pe[c].y * iv;
            p4.z = pe[c].z * iv; p4.w = pe[c].w * iv;
            *(float4*)(ap + (size_t)row * N + jc * 64 + j4 * 4) = p4;
            uint2 hh, ll;
            split2(p4.x, p4.y, hh.x, ll.x);
            split2(p4.z, p4.w, hh.y, ll.y);
            int idx = row * 64 + (((j4 >> 1) ^ (row & 7)) * 8) + (j4 & 1) * 4;
            *(uint2*)(Ph + idx) = hh;
            *(uint2*)(Pl + idx) = ll;
        }
        // Stage V tile: plain b128 copies, granule-swizzled rows (conflict-free).
        #pragma unroll
        for (int c = 0; c < 4; ++c) {
            int flat = c * 256 + t;
            int d = flat >> 3, g = flat & 7;
            int sidx = d * 64 + ((g ^ (d & 7)) * 8);
            *(float4*)(Vh + sidx) = fh[c];
            *(float4*)(Vl + sidx) = fl[c];
        }
        __syncthreads();
        // Prefetch next chunk (hides HBM latency under MFMA below).
        if (jc < 31) {
            #pragma unroll
            for (int c = 0; c < 4; ++c) {
                int flat = c * 256 + t;
                pe[c] = *(const float4*)(ap + (size_t)(flat >> 4) * N + (jc + 1) * 64 + (flat & 15) * 4);
                int d = flat >> 3, g = flat & 7;
                fh[c] = *(const float4*)(vhp + (size_t)d * N + (jc + 1) * 64 + g * 8);
                fl[c] = *(const float4*)(vlp + (size_t)d * N + (jc + 1) * 64 + g * 8);
            }
        }
        // Compute: 2 K-steps of 32 over this chunk's 64 j.
        #pragma unroll
        for (int ksj = 0; ksj < 2; ++ksj) {
            s16x8 pah[2], pal[2], bh[4], bl[4];
            #pragma unroll
            for (int ti = 0; ti < 2; ++ti) {
                int row = rg + ti * 16 + l15;
                int idx = row * 64 + (((ksj * 4 + l4) ^ (row & 7)) * 8);
                pah[ti] = *(const s16x8*)(Ph + idx);
                pal[ti] = *(const s16x8*)(Pl + idx);
            }
            #pragma unroll
            for (int tj = 0; tj < 4; ++tj) {
                int d = dg + tj * 16 + l15;
                int idx = d * 64 + (((ksj * 4 + l4) ^ (d & 7)) * 8);
                bh[tj] = *(const s16x8*)(Vh + idx);
                bl[tj] = *(const s16x8*)(Vl + idx);
            }
            #pragma unroll
            for (int ti = 0; ti < 2; ++ti)
                #pragma unroll
                for (int tj = 0; tj < 4; ++tj) {
                    acc[ti][tj] = __builtin_amdgcn_mfma_f32_16x16x32_bf16(pah[ti], bh[tj], acc[ti][tj], 0, 0, 0);
                    acc[ti][tj] = __builtin_amdgcn_mfma_f32_16x16x32_bf16(pah[ti], bl[tj], acc[ti][tj], 0, 0, 0);
                    acc[ti][tj] = __builtin_amdgcn_mfma_f32_16x16x32_bf16(pal[ti], bh[tj], acc[ti][tj], 0, 0, 0);
                }
        }
    }

    // Epilogue: write O (also overwrites the rowsum scratch at d=0).
    #pragma unroll
    for (int ti = 0; ti < 2; ++ti)
        #pragma unroll
        for (int r = 0; r < 4; ++r) {
            int row = rg + ti * 16 + l4 * 4 + r;
            #pragma unroll
            for (int tj = 0; tj < 4; ++tj)
                op[(size_t)row * D + dg + tj * 16 + l15] = acc[ti][tj][r];
        }
}

// ---------------------------------------------------------------------------
// Kernel 2 (fallback, ws too small): previous passing version with in-kernel
// V transpose. Kept verbatim for safety.
// ---------------------------------------------------------------------------
__global__ __launch_bounds__(256) void pv_fb_kernel(const float* __restrict__ v,
                                                    float* __restrict__ attn,
                                                    float* __restrict__ outp) {
    __shared__ unsigned short Ph[64 * 64], Pl[64 * 64];
    __shared__ unsigned short Vth[128 * 64], Vtl[128 * 64];
    __shared__ float invs[64];
    const int t  = threadIdx.x;
    const int b  = blockIdx.y;
    const int ib = blockIdx.x * 64;
    float* ap       = attn + ((size_t)b * N + ib) * N;
    const float* vp = v + (size_t)b * N * D;
    float* op       = outp + ((size_t)b * N + ib) * D;

    if (t < 64) invs[t] = 1.0f / op[(size_t)t * D];

    const int lane = t & 63;
    const int w    = t >> 6;
    const int rg   = (w >> 1) * 32;
    const int dg   = (w & 1) * 64;
    const int l15  = lane & 15;
    const int l4   = lane >> 4;

    f32x4 acc[2][4] = {};

    float4 pe[4], va[4], vb[4];
    #pragma unroll
    for (int c = 0; c < 4; ++c) {
        int flat = c * 256 + t;
        pe[c] = *(const float4*)(ap + (size_t)(flat >> 4) * N + (flat & 15) * 4);
        int jp = flat >> 5, d4 = flat & 31;
        va[c] = *(const float4*)(vp + (size_t)(jp * 2) * D + d4 * 4);
        vb[c] = *(const float4*)(vp + (size_t)(jp * 2 + 1) * D + d4 * 4);
    }

    for (int jc = 0; jc < 32; ++jc) {
        __syncthreads();
        #pragma unroll
        for (int c = 0; c < 4; ++c) {
            int flat = c * 256 + t;
            int row = flat >> 4, j4 = flat & 15;
            float iv = invs[row];
            float4 p4;
            p4.x = pe[c].x * iv; p4.y = pe[c].y * iv;
            p4.z = pe[c].z * iv; p4.w = pe[c].w * iv;
            *(float4*)(ap + (size_t)row * N + jc * 64 + j4 * 4) = p4;
            uint2 hh, ll;
            split2(p4.x, p4.y, hh.x, ll.x);
            split2(p4.z, p4.w, hh.y, ll.y);
            int idx = row * 64 + (((j4 >> 1) ^ (row & 7)) * 8) + (j4 & 1) * 4;
            *(uint2*)(Ph + idx) = hh;
            *(uint2*)(Pl + idx) = ll;
        }
        #pragma unroll
        for (int c = 0; c < 4; ++c) {
            int flat = c * 256 + t;
            int jp = flat >> 5, d4 = flat & 31;
            int j = jp * 2;
            float4 v0 = va[c], v1 = vb[c];
            #pragma unroll
            for (int e = 0; e < 4; ++e) {
                float x0 = (&v0.x)[e], x1 = (&v1.x)[e];
                unsigned h, l;
                split2(x0, x1, h, l);
                int d = d4 * 4 + e;
                int idx = d * 64 + (((j >> 3) ^ (d & 7)) * 8) + (j & 7);
                *(unsigned*)(Vth + idx) = h;
                *(unsigned*)(Vtl + idx) = l;
            }
        }
        __syncthreads();
        if (jc < 31) {
            #pragma unroll
            for (int c = 0; c < 4; ++c) {
                int flat = c * 256 + t;
                pe[c] = *(const float4*)(ap + (size_t)(flat >> 4) * N + (jc + 1) * 64 + (flat & 15) * 4);
                int jp = flat >> 5, d4 = flat & 31;
                va[c] = *(const float4*)(vp + (size_t)((jc + 1) * 64 + jp * 2) * D + d4 * 4);
                vb[c] = *(const float4*)(vp + (size_t)((jc + 1) * 64 + jp * 2 + 1) * D + d4 * 4);
            }
        }
        #pragma unroll
        for (int ksj = 0; ksj < 2; ++ksj) {
            s16x8 pah[2], pal[2], bh[4], bl[4];
            #pragma unroll
            for (int ti = 0; ti < 2; ++ti) {
                int row = rg + ti * 16 + l15;
                int idx = row * 64 + (((ksj * 4 + l4) ^ (row & 7)) * 8);
                pah[ti] = *(const s16x8*)(Ph + idx);
                pal[ti] = *(const s16x8*)(Pl + idx);
            }
            #pragma unroll
            for (int tj = 0; tj < 4; ++tj) {
                int d = dg + tj * 16 + l15;
                int idx = d * 64 + (((ksj * 4 + l4) ^ (d & 7)) * 8);
                bh[tj] = *(const s16x8*)(Vth + idx);
                bl[tj] = *(const s16x8*)(Vtl + idx);
            }
            #pragma unroll
            for (int ti = 0; ti < 2; ++ti)
                #pragma unroll
                for (int tj = 0; tj < 4; ++tj) {
                    acc[ti][tj] = __builtin_amdgcn_mfma_f32_16x16x32_bf16(pah[ti], bh[tj], acc[ti][tj], 0, 0, 0);
                    acc[ti][tj] = __builtin_amdgcn_mfma_f32_16x16x32_bf16(pah[ti], bl[tj], acc[ti][tj], 0, 0, 0);
                    acc[ti][tj] = __builtin_amdgcn_mfma_f32_16x16x32_bf16(pal[ti], bh[tj], acc[ti][tj], 0, 0, 0);
                }
        }
    }

    #pragma unroll
    for (int ti = 0; ti < 2; ++ti)
        #pragma unroll
        for (int r = 0; r < 4; ++r) {
            int row = rg + ti * 16 + l4 * 4 + r;
            #pragma unroll
            for (int tj = 0; tj < 4; ++tj)
                op[(size_t)row * D + dg + tj * 16 + l15] = acc[ti][tj][r];
        }
}

extern "C" void kernel_launch(void* const* d_in, const int* in_sizes, int n_in,
                              void* d_out, int out_size, void* d_ws, size_t ws_size,
                              hipStream_t stream) {
    const float* q = (const float*)d_in[0];
    const float* k = (const float*)d_in[1];
    const float* v = (const float*)d_in[2];
    float* out  = (float*)d_out;                    // [16,2048,128]
    float* attn = out + (size_t)BB * N * D;         // [16,2048,2048]

    const size_t vt_elems = (size_t)BB * D * N;     // 4,194,304
    const bool use_ws = ws_size >= vt_elems * 2 * sizeof(unsigned short);  // 16.78 MB

    zero_kernel<<<1024, 256, 0, stream>>>((float4*)out, BB * N * D / 4);
    if (use_ws) {
        unsigned short* vth = (unsigned short*)d_ws;
        unsigned short* vtl = vth + vt_elems;
        vt_kernel<<<dim3(N / 32, 2, BB), 256, 0, stream>>>(v, vth, vtl);
        qk_kernel<<<dim3(N / 128, N / 128, BB), 256, 0, stream>>>(q, k, attn, out);
        pv_pre_kernel<<<dim3(N / 64, BB), 256, 0, stream>>>(vth, vtl, attn, out);
    } else {
        qk_kernel<<<dim3(N / 128, N / 128, BB), 256, 0, stream>>>(q, k, attn, out);
        pv_fb_kernel<<<dim3(N / 64, BB), 256, 0, stream>>>(v, attn, out);
    }
}

// Round 4
// 568.051 us; speedup vs baseline: 1.2535x; 1.2535x over previous
//
#include <hip/hip_runtime.h>

#define N 2048
#define D 128
#define BB 16

typedef __attribute__((ext_vector_type(8))) short s16x8;   // 8 bf16 = 4 VGPR
typedef __attribute__((ext_vector_type(4))) float f32x4;   // MFMA acc

// Split two fp32 into packed bf16 hi (h) and bf16 lo (l) words.
// hi = truncate-to-bf16(x); lo = truncate-to-bf16(x - hi).  ~2^-16 rel total.
__device__ __forceinline__ void split2(float x0, float x1, unsigned& h, unsigned& l) {
    unsigned b0 = __float_as_uint(x0), b1 = __float_as_uint(x1);
    float r0 = x0 - __uint_as_float(b0 & 0xffff0000u);
    float r1 = x1 - __uint_as_float(b1 & 0xffff0000u);
    h = (b0 >> 16) | (b1 & 0xffff0000u);
    l = (__float_as_uint(r0) >> 16) | (__float_as_uint(r1) & 0xffff0000u);
}

__device__ __forceinline__ s16x8 pack16(uint4 u) {
    union { uint4 a; s16x8 b; } x; x.a = u; return x.b;
}

// ---------------------------------------------------------------------------
// Kernel 0: zero the `out` region (rowsum accumulators live at out[b][i][0]).
// ---------------------------------------------------------------------------
__global__ __launch_bounds__(256) void zero_kernel(float4* __restrict__ p, int n4) {
    int i = blockIdx.x * 256 + threadIdx.x;
    const int stride = gridDim.x * 256;
    for (; i < n4; i += stride) p[i] = make_float4(0.f, 0.f, 0.f, 0.f);
}

// ---------------------------------------------------------------------------
// Kernel V: pre-transpose + hi/lo split of V into workspace:
//   Vt_h/Vt_l [b][d=128][n=2048] bf16.
// ---------------------------------------------------------------------------
__global__ __launch_bounds__(256) void vt_kernel(const float* __restrict__ v,
                                                 unsigned short* __restrict__ vth,
                                                 unsigned short* __restrict__ vtl) {
    const int t    = threadIdx.x;
    const int lane = t & 63;
    const int w    = t >> 6;
    const int b    = blockIdx.z;
    const int n0   = blockIdx.x * 32 + w * 8;
    const int d    = blockIdx.y * 64 + lane;
    const float* vp = v + ((size_t)b * N + n0) * D + d;
    float x[8];
    #pragma unroll
    for (int i = 0; i < 8; ++i) x[i] = vp[(size_t)i * D];
    uint4 h, l;
    split2(x[0], x[1], h.x, l.x);
    split2(x[2], x[3], h.y, l.y);
    split2(x[4], x[5], h.z, l.z);
    split2(x[6], x[7], h.w, l.w);
    size_t idx = ((size_t)b * D + d) * N + n0;
    *(uint4*)(vth + idx) = h;
    *(uint4*)(vtl + idx) = l;
}

// ---------------------------------------------------------------------------
// Kernel 1: ROWSUM-ONLY pass. s = Q@K^T via bf16 hi/lo MFMA (identical
// arithmetic to the fused kernel), rs = sum(exp(s)) accumulated via
// atomicAdd into out[b][i][0]. NO attn store.
// ---------------------------------------------------------------------------
__global__ __launch_bounds__(256) void qs_kernel(const float* __restrict__ q,
                                                 const float* __restrict__ k,
                                                 float* __restrict__ outp) {
    __shared__ unsigned short Qh[128 * 32], Ql[128 * 32];
    __shared__ unsigned short Kh[128 * 32], Kl[128 * 32];
    const int t  = threadIdx.x;
    const int b  = blockIdx.z;
    const int ib = blockIdx.y * 128;
    const int jb = blockIdx.x * 128;
    const float* qp = q + ((size_t)b * N + ib) * D;
    const float* kp = k + ((size_t)b * N + jb) * D;

    const int lane = t & 63;
    const int w    = t >> 6;
    const int wr   = (w >> 1) * 64;
    const int wc   = (w & 1) * 64;
    const int l15  = lane & 15;
    const int l4   = lane >> 4;

    f32x4 acc[4][4] = {};

    for (int ks = 0; ks < 4; ++ks) {
        __syncthreads();
        #pragma unroll
        for (int c = 0; c < 4; ++c) {
            int flat = c * 256 + t;
            int row  = flat >> 3;
            int f4   = flat & 7;
            float4 qv = *(const float4*)(qp + (size_t)row * D + ks * 32 + f4 * 4);
            float4 kv = *(const float4*)(kp + (size_t)row * D + ks * 32 + f4 * 4);
            int idx = row * 32 + (((f4 >> 1) ^ (row & 3)) * 8) + (f4 & 1) * 4;
            uint2 hh, ll;
            split2(qv.x, qv.y, hh.x, ll.x);
            split2(qv.z, qv.w, hh.y, ll.y);
            *(uint2*)(Qh + idx) = hh;
            *(uint2*)(Ql + idx) = ll;
            split2(kv.x, kv.y, hh.x, ll.x);
            split2(kv.z, kv.w, hh.y, ll.y);
            *(uint2*)(Kh + idx) = hh;
            *(uint2*)(Kl + idx) = ll;
        }
        __syncthreads();

        s16x8 ah[4], al[4], bh[4], bl[4];
        #pragma unroll
        for (int ti = 0; ti < 4; ++ti) {
            int row = wr + ti * 16 + l15;
            int idx = row * 32 + ((l4 ^ (row & 3)) * 8);
            ah[ti] = *(const s16x8*)(Qh + idx);
            al[ti] = *(const s16x8*)(Ql + idx);
        }
        #pragma unroll
        for (int tj = 0; tj < 4; ++tj) {
            int row = wc + tj * 16 + l15;
            int idx = row * 32 + ((l4 ^ (row & 3)) * 8);
            bh[tj] = *(const s16x8*)(Kh + idx);
            bl[tj] = *(const s16x8*)(Kl + idx);
        }
        #pragma unroll
        for (int ti = 0; ti < 4; ++ti)
            #pragma unroll
            for (int tj = 0; tj < 4; ++tj) {
                acc[ti][tj] = __builtin_amdgcn_mfma_f32_16x16x32_bf16(ah[ti], bh[tj], acc[ti][tj], 0, 0, 0);
                acc[ti][tj] = __builtin_amdgcn_mfma_f32_16x16x32_bf16(ah[ti], bl[tj], acc[ti][tj], 0, 0, 0);
                acc[ti][tj] = __builtin_amdgcn_mfma_f32_16x16x32_bf16(al[ti], bh[tj], acc[ti][tj], 0, 0, 0);
            }
    }

    #pragma unroll
    for (int ti = 0; ti < 4; ++ti) {
        #pragma unroll
        for (int r = 0; r < 4; ++r) {
            int row = ib + wr + ti * 16 + l4 * 4 + r;
            float rs = 0.f;
            #pragma unroll
            for (int tj = 0; tj < 4; ++tj) rs += __expf(acc[ti][tj][r]);
            rs += __shfl_xor(rs, 1);
            rs += __shfl_xor(rs, 2);
            rs += __shfl_xor(rs, 4);
            rs += __shfl_xor(rs, 8);
            if (l15 == 0) atomicAdd(outp + ((size_t)b * N + row) * D, rs);
        }
    }
}

// ---------------------------------------------------------------------------
// Kernel 2 (fused): recompute s = Q@K^T per 64-row tile, P = exp(s)*inv
// (inv from qs rowsums), write normalized attn ONCE, and accumulate
// O = P@V via bf16 hi/lo MFMA — attn is never read back.
// Block: 64 Q-rows, 4 waves (wave w owns rows w*16..+15), j-chunks of 64.
// LDS: K-chunk hi/lo (32 KB, aliased with per-wave P scratch) + Vt hi/lo
// (32 KB) = 64 KB -> 2 blocks/CU. Q A-frags + O acc live in registers.
// ---------------------------------------------------------------------------
__global__ __launch_bounds__(256, 2) void fused_kernel(const float* __restrict__ q,
                                                       const float* __restrict__ k,
                                                       const unsigned short* __restrict__ vth,
                                                       const unsigned short* __restrict__ vtl,
                                                       float* __restrict__ attn,
                                                       float* __restrict__ outp) {
    __shared__ unsigned short Kh[64 * 128], Kl[64 * 128];   // 16+16 KB (K chunk)
    __shared__ unsigned short Vh[128 * 64], Vl[128 * 64];   // 16+16 KB (Vt chunk)
    float* Pf = (float*)Kh;   // aliased P scratch: 4 waves x [16][64] f32 = 16 KB

    const int t = threadIdx.x, lane = t & 63, w = t >> 6;
    const int b = blockIdx.y, ib = blockIdx.x * 64;
    const int l15 = lane & 15, l4 = lane >> 4;
    const float* qp = q + ((size_t)b * N + ib) * D;
    const float* kp = k + (size_t)b * N * D;
    const unsigned short* vhp = vth + (size_t)b * D * N;
    const unsigned short* vlp = vtl + (size_t)b * D * N;
    float* ap = attn + ((size_t)b * N + ib) * N;
    float* op = outp + ((size_t)b * N + ib) * D;

    // inv rowsums for the 4 rows this thread epilogues (C/D row = l4*4+r).
    float inv[4];
    #pragma unroll
    for (int r = 0; r < 4; ++r)
        inv[r] = 1.0f / op[(size_t)(w * 16 + l4 * 4 + r) * D];

    // Q A-frags in registers: Q[w*16+l15][ks*32 + l4*8 .. +7], hi/lo.
    s16x8 qh[4], ql[4];
    {
        const float* qrow = qp + (size_t)(w * 16 + l15) * D;
        #pragma unroll
        for (int ks = 0; ks < 4; ++ks) {
            float4 x0 = *(const float4*)(qrow + ks * 32 + l4 * 8);
            float4 x1 = *(const float4*)(qrow + ks * 32 + l4 * 8 + 4);
            uint4 h, l;
            split2(x0.x, x0.y, h.x, l.x);
            split2(x0.z, x0.w, h.y, l.y);
            split2(x1.x, x1.y, h.z, l.z);
            split2(x1.z, x1.w, h.w, l.w);
            qh[ks] = pack16(h);
            ql[ks] = pack16(l);
        }
    }

    f32x4 oacc[8] = {};

    // Prefetch chunk 0: K rows (fp32) + Vt rows (pre-split bf16).
    float4 kf[8];
    uint4 fh[4], fl[4];
    #pragma unroll
    for (int c = 0; c < 8; ++c) {
        int flat4 = c * 256 + t;
        int row = flat4 >> 5, f4 = flat4 & 31;
        kf[c] = *(const float4*)(kp + (size_t)row * D + f4 * 4);
    }
    #pragma unroll
    for (int c = 0; c < 4; ++c) {
        int flat = c * 256 + t;
        int d = flat >> 3, g = flat & 7;
        fh[c] = *(const uint4*)(vhp + (size_t)d * N + g * 8);
        fl[c] = *(const uint4*)(vlp + (size_t)d * N + g * 8);
    }

    for (int jc = 0; jc < 32; ++jc) {
        __syncthreads();   // (1) prev chunk's PV reads of Vh/Vl and Pf(=Kh) done
        // Stage K chunk [64 j][128 d] hi/lo, 16B-granule XOR swizzle (row&7).
        #pragma unroll
        for (int c = 0; c < 8; ++c) {
            int flat4 = c * 256 + t;
            int row = flat4 >> 5, f4 = flat4 & 31;
            uint2 hh, ll;
            split2(kf[c].x, kf[c].y, hh.x, ll.x);
            split2(kf[c].z, kf[c].w, hh.y, ll.y);
            int idx = row * 128 + (((f4 >> 1) ^ (row & 7)) * 8) + (f4 & 1) * 4;
            *(uint2*)(Kh + idx) = hh;
            *(uint2*)(Kl + idx) = ll;
        }
        // Stage Vt chunk [128 d][64 j] hi/lo (same layout as verified pv_pre).
        #pragma unroll
        for (int c = 0; c < 4; ++c) {
            int flat = c * 256 + t;
            int d = flat >> 3, g = flat & 7;
            int idx = d * 64 + ((g ^ (d & 7)) * 8);
            *(uint4*)(Vh + idx) = fh[c];
            *(uint4*)(Vl + idx) = fl[c];
        }
        __syncthreads();   // (2) staging visible
        // Prefetch chunk jc+1 (latency hides under QK+PV below).
        if (jc < 31) {
            #pragma unroll
            for (int c = 0; c < 8; ++c) {
                int flat4 = c * 256 + t;
                int row = flat4 >> 5, f4 = flat4 & 31;
                kf[c] = *(const float4*)(kp + (size_t)((jc + 1) * 64 + row) * D + f4 * 4);
            }
            #pragma unroll
            for (int c = 0; c < 4; ++c) {
                int flat = c * 256 + t;
                int d = flat >> 3, g = flat & 7;
                fh[c] = *(const uint4*)(vhp + (size_t)d * N + (jc + 1) * 64 + g * 8);
                fl[c] = *(const uint4*)(vlp + (size_t)d * N + (jc + 1) * 64 + g * 8);
            }
        }
        // QK^T: rows w*16..+15 x this chunk's 64 cols. Same per-element
        // accumulation order as qs_kernel -> bit-identical s.
        f32x4 sacc[4] = {};
        #pragma unroll
        for (int ks = 0; ks < 4; ++ks) {
            s16x8 bh[4], bl[4];
            #pragma unroll
            for (int tj = 0; tj < 4; ++tj) {
                int row = tj * 16 + l15;
                int idx = row * 128 + (((ks * 4 + l4) ^ (row & 7)) * 8);
                bh[tj] = *(const s16x8*)(Kh + idx);
                bl[tj] = *(const s16x8*)(Kl + idx);
            }
            #pragma unroll
            for (int tj = 0; tj < 4; ++tj) {
                sacc[tj] = __builtin_amdgcn_mfma_f32_16x16x32_bf16(qh[ks], bh[tj], sacc[tj], 0, 0, 0);
                sacc[tj] = __builtin_amdgcn_mfma_f32_16x16x32_bf16(qh[ks], bl[tj], sacc[tj], 0, 0, 0);
                sacc[tj] = __builtin_amdgcn_mfma_f32_16x16x32_bf16(ql[ks], bh[tj], sacc[tj], 0, 0, 0);
            }
        }
        __syncthreads();   // (3) all waves done reading Kh/Kl -> Pf alias safe
        // P = exp(s)*inv: write attn (only write of attn in the pipeline)
        // and per-wave Pf scratch (granule-swizzled for the transpose read).
        float* pw = Pf + w * (16 * 64);
        #pragma unroll
        for (int r = 0; r < 4; ++r) {
            int row = l4 * 4 + r;
            float* arow = ap + (size_t)(w * 16 + row) * N + jc * 64;
            #pragma unroll
            for (int tj = 0; tj < 4; ++tj) {
                float pv = __expf(sacc[tj][r]) * inv[r];
                arow[tj * 16 + l15] = pv;
                int gw = (tj * 4 + (l15 >> 2)) ^ ((row & 7) << 1);
                pw[row * 64 + gw * 4 + (l15 & 3)] = pv;
            }
        }
        // PV: A = P rows (wave-local Pf readback, lgkmcnt ordered), B = Vt.
        #pragma unroll
        for (int ks2 = 0; ks2 < 2; ++ks2) {
            int g0 = (ks2 * 8 + l4 * 2) ^ ((l15 & 7) << 1);   // even; pair stays ordered
            float4 p0 = *(const float4*)(pw + l15 * 64 + g0 * 4);
            float4 p1 = *(const float4*)(pw + l15 * 64 + g0 * 4 + 4);
            uint4 h, l;
            split2(p0.x, p0.y, h.x, l.x);
            split2(p0.z, p0.w, h.y, l.y);
            split2(p1.x, p1.y, h.z, l.z);
            split2(p1.z, p1.w, h.w, l.w);
            s16x8 pah = pack16(h), pal = pack16(l);
            #pragma unroll
            for (int df = 0; df < 8; ++df) {
                int dr = df * 16 + l15;
                int idx = dr * 64 + (((ks2 * 4 + l4) ^ (dr & 7)) * 8);
                s16x8 vbh = *(const s16x8*)(Vh + idx);
                s16x8 vbl = *(const s16x8*)(Vl + idx);
                oacc[df] = __builtin_amdgcn_mfma_f32_16x16x32_bf16(pah, vbh, oacc[df], 0, 0, 0);
                oacc[df] = __builtin_amdgcn_mfma_f32_16x16x32_bf16(pah, vbl, oacc[df], 0, 0, 0);
                oacc[df] = __builtin_amdgcn_mfma_f32_16x16x32_bf16(pal, vbh, oacc[df], 0, 0, 0);
            }
        }
    }

    // Epilogue: write O (overwrites the rowsum scratch at d=0).
    #pragma unroll
    for (int r = 0; r < 4; ++r) {
        int row = w * 16 + l4 * 4 + r;
        #pragma unroll
        for (int df = 0; df < 8; ++df)
            op[(size_t)row * D + df * 16 + l15] = oacc[df][r];
    }
}

// ---------------------------------------------------------------------------
// Fallback path (ws too small): round-2 passing kernels, verbatim.
// ---------------------------------------------------------------------------
__global__ __launch_bounds__(256) void qk_kernel(const float* __restrict__ q,
                                                 const float* __restrict__ k,
                                                 float* __restrict__ attn,
                                                 float* __restrict__ outp) {
    __shared__ unsigned short Qh[128 * 32], Ql[128 * 32];
    __shared__ unsigned short Kh[128 * 32], Kl[128 * 32];
    const int t  = threadIdx.x;
    const int b  = blockIdx.z;
    const int ib = blockIdx.y * 128;
    const int jb = blockIdx.x * 128;
    const float* qp = q + ((size_t)b * N + ib) * D;
    const float* kp = k + ((size_t)b * N + jb) * D;

    const int lane = t & 63;
    const int w    = t >> 6;
    const int wr   = (w >> 1) * 64;
    const int wc   = (w & 1) * 64;
    const int l15  = lane & 15;
    const int l4   = lane >> 4;

    f32x4 acc[4][4] = {};

    for (int ks = 0; ks < 4; ++ks) {
        __syncthreads();
        #pragma unroll
        for (int c = 0; c < 4; ++c) {
            int flat = c * 256 + t;
            int row  = flat >> 3;
            int f4   = flat & 7;
            float4 qv = *(const float4*)(qp + (size_t)row * D + ks * 32 + f4 * 4);
            float4 kv = *(const float4*)(kp + (size_t)row * D + ks * 32 + f4 * 4);
            int idx = row * 32 + (((f4 >> 1) ^ (row & 3)) * 8) + (f4 & 1) * 4;
            uint2 hh, ll;
            split2(qv.x, qv.y, hh.x, ll.x);
            split2(qv.z, qv.w, hh.y, ll.y);
            *(uint2*)(Qh + idx) = hh;
            *(uint2*)(Ql + idx) = ll;
            split2(kv.x, kv.y, hh.x, ll.x);
            split2(kv.z, kv.w, hh.y, ll.y);
            *(uint2*)(Kh + idx) = hh;
            *(uint2*)(Kl + idx) = ll;
        }
        __syncthreads();

        s16x8 ah[4], al[4], bh[4], bl[4];
        #pragma unroll
        for (int ti = 0; ti < 4; ++ti) {
            int row = wr + ti * 16 + l15;
            int idx = row * 32 + ((l4 ^ (row & 3)) * 8);
            ah[ti] = *(const s16x8*)(Qh + idx);
            al[ti] = *(const s16x8*)(Ql + idx);
        }
        #pragma unroll
        for (int tj = 0; tj < 4; ++tj) {
            int row = wc + tj * 16 + l15;
            int idx = row * 32 + ((l4 ^ (row & 3)) * 8);
            bh[tj] = *(const s16x8*)(Kh + idx);
            bl[tj] = *(const s16x8*)(Kl + idx);
        }
        #pragma unroll
        for (int ti = 0; ti < 4; ++ti)
            #pragma unroll
            for (int tj = 0; tj < 4; ++tj) {
                acc[ti][tj] = __builtin_amdgcn_mfma_f32_16x16x32_bf16(ah[ti], bh[tj], acc[ti][tj], 0, 0, 0);
                acc[ti][tj] = __builtin_amdgcn_mfma_f32_16x16x32_bf16(ah[ti], bl[tj], acc[ti][tj], 0, 0, 0);
                acc[ti][tj] = __builtin_amdgcn_mfma_f32_16x16x32_bf16(al[ti], bh[tj], acc[ti][tj], 0, 0, 0);
            }
    }

    #pragma unroll
    for (int ti = 0; ti < 4; ++ti) {
        #pragma unroll
        for (int r = 0; r < 4; ++r) {
            int row = ib + wr + ti * 16 + l4 * 4 + r;
            float* arow = attn + ((size_t)b * N + row) * N + jb + wc;
            float rs = 0.f;
            #pragma unroll
            for (int tj = 0; tj < 4; ++tj) {
                float e = __expf(acc[ti][tj][r]);
                arow[tj * 16 + l15] = e;
                rs += e;
            }
            rs += __shfl_xor(rs, 1);
            rs += __shfl_xor(rs, 2);
            rs += __shfl_xor(rs, 4);
            rs += __shfl_xor(rs, 8);
            if (l15 == 0) atomicAdd(outp + ((size_t)b * N + row) * D, rs);
        }
    }
}

__global__ __launch_bounds__(256) void pv_fb_kernel(const float* __restrict__ v,
                                                    float* __restrict__ attn,
                                                    float* __restrict__ outp) {
    __shared__ unsigned short Ph[64 * 64], Pl[64 * 64];
    __shared__ unsigned short Vth[128 * 64], Vtl[128 * 64];
    __shared__ float invs[64];
    const int t  = threadIdx.x;
    const int b  = blockIdx.y;
    const int ib = blockIdx.x * 64;
    float* ap       = attn + ((size_t)b * N + ib) * N;
    const float* vp = v + (size_t)b * N * D;
    float* op       = outp + ((size_t)b * N + ib) * D;

    if (t < 64) invs[t] = 1.0f / op[(size_t)t * D];

    const int lane = t & 63;
    const int w    = t >> 6;
    const int rg   = (w >> 1) * 32;
    const int dg   = (w & 1) * 64;
    const int l15  = lane & 15;
    const int l4   = lane >> 4;

    f32x4 acc[2][4] = {};

    float4 pe[4], va[4], vb[4];
    #pragma unroll
    for (int c = 0; c < 4; ++c) {
        int flat = c * 256 + t;
        pe[c] = *(const float4*)(ap + (size_t)(flat >> 4) * N + (flat & 15) * 4);
        int jp = flat >> 5, d4 = flat & 31;
        va[c] = *(const float4*)(vp + (size_t)(jp * 2) * D + d4 * 4);
        vb[c] = *(const float4*)(vp + (size_t)(jp * 2 + 1) * D + d4 * 4);
    }

    for (int jc = 0; jc < 32; ++jc) {
        __syncthreads();
        #pragma unroll
        for (int c = 0; c < 4; ++c) {
            int flat = c * 256 + t;
            int row = flat >> 4, j4 = flat & 15;
            float iv = invs[row];
            float4 p4;
            p4.x = pe[c].x * iv; p4.y = pe[c].y * iv;
            p4.z = pe[c].z * iv; p4.w = pe[c].w * iv;
            *(float4*)(ap + (size_t)row * N + jc * 64 + j4 * 4) = p4;
            uint2 hh, ll;
            split2(p4.x, p4.y, hh.x, ll.x);
            split2(p4.z, p4.w, hh.y, ll.y);
            int idx = row * 64 + (((j4 >> 1) ^ (row & 7)) * 8) + (j4 & 1) * 4;
            *(uint2*)(Ph + idx) = hh;
            *(uint2*)(Pl + idx) = ll;
        }
        #pragma unroll
        for (int c = 0; c < 4; ++c) {
            int flat = c * 256 + t;
            int jp = flat >> 5, d4 = flat & 31;
            int j = jp * 2;
            float4 v0 = va[c], v1 = vb[c];
            #pragma unroll
            for (int e = 0; e < 4; ++e) {
                float x0 = (&v0.x)[e], x1 = (&v1.x)[e];
                unsigned h, l;
                split2(x0, x1, h, l);
                int d = d4 * 4 + e;
                int idx = d * 64 + (((j >> 3) ^ (d & 7)) * 8) + (j & 7);
                *(unsigned*)(Vth + idx) = h;
                *(unsigned*)(Vtl + idx) = l;
            }
        }
        __syncthreads();
        if (jc < 31) {
            #pragma unroll
            for (int c = 0; c < 4; ++c) {
                int flat = c * 256 + t;
                pe[c] = *(const float4*)(ap + (size_t)(flat >> 4) * N + (jc + 1) * 64 + (flat & 15) * 4);
                int jp = flat >> 5, d4 = flat & 31;
                va[c] = *(const float4*)(vp + (size_t)((jc + 1) * 64 + jp * 2) * D + d4 * 4);
                vb[c] = *(const float4*)(vp + (size_t)((jc + 1) * 64 + jp * 2 + 1) * D + d4 * 4);
            }
        }
        #pragma unroll
        for (int ksj = 0; ksj < 2; ++ksj) {
            s16x8 pah[2], pal[2], bh[4], bl[4];
            #pragma unroll
            for (int ti = 0; ti < 2; ++ti) {
                int row = rg + ti * 16 + l15;
                int idx = row * 64 + (((ksj * 4 + l4) ^ (row & 7)) * 8);
                pah[ti] = *(const s16x8*)(Ph + idx);
                pal[ti] = *(const s16x8*)(Pl + idx);
            }
            #pragma unroll
            for (int tj = 0; tj < 4; ++tj) {
                int d = dg + tj * 16 + l15;
                int idx = d * 64 + (((ksj * 4 + l4) ^ (d & 7)) * 8);
                bh[tj] = *(const s16x8*)(Vth + idx);
                bl[tj] = *(const s16x8*)(Vtl + idx);
            }
            #pragma unroll
            for (int ti = 0; ti < 2; ++ti)
                #pragma unroll
                for (int tj = 0; tj < 4; ++tj) {
                    acc[ti][tj] = __builtin_amdgcn_mfma_f32_16x16x32_bf16(pah[ti], bh[tj], acc[ti][tj], 0, 0, 0);
                    acc[ti][tj] = __builtin_amdgcn_mfma_f32_16x16x32_bf16(pah[ti], bl[tj], acc[ti][tj], 0, 0, 0);
                    acc[ti][tj] = __builtin_amdgcn_mfma_f32_16x16x32_bf16(pal[ti], bh[tj], acc[ti][tj], 0, 0, 0);
                }
        }
    }

    #pragma unroll
    for (int ti = 0; ti < 2; ++ti)
        #pragma unroll
        for (int r = 0; r < 4; ++r) {
            int row = rg + ti * 16 + l4 * 4 + r;
            #pragma unroll
            for (int tj = 0; tj < 4; ++tj)
                op[(size_t)row * D + dg + tj * 16 + l15] = acc[ti][tj][r];
        }
}

extern "C" void kernel_launch(void* const* d_in, const int* in_sizes, int n_in,
                              void* d_out, int out_size, void* d_ws, size_t ws_size,
                              hipStream_t stream) {
    const float* q = (const float*)d_in[0];
    const float* k = (const float*)d_in[1];
    const float* v = (const float*)d_in[2];
    float* out  = (float*)d_out;                    // [16,2048,128]
    float* attn = out + (size_t)BB * N * D;         // [16,2048,2048]

    const size_t vt_elems = (size_t)BB * D * N;     // 4,194,304
    const bool use_ws = ws_size >= vt_elems * 2 * sizeof(unsigned short);  // 16.78 MB

    zero_kernel<<<1024, 256, 0, stream>>>((float4*)out, BB * N * D / 4);
    if (use_ws) {
        unsigned short* vth = (unsigned short*)d_ws;
        unsigned short* vtl = vth + vt_elems;
        vt_kernel<<<dim3(N / 32, 2, BB), 256, 0, stream>>>(v, vth, vtl);
        qs_kernel<<<dim3(N / 128, N / 128, BB), 256, 0, stream>>>(q, k, out);
        fused_kernel<<<dim3(N / 64, BB), 256, 0, stream>>>(q, k, vth, vtl, attn, out);
    } else {
        qk_kernel<<<dim3(N / 128, N / 128, BB), 256, 0, stream>>>(q, k, attn, out);
        pv_fb_kernel<<<dim3(N / 64, BB), 256, 0, stream>>>(v, attn, out);
    }
}

// Round 5
// 514.834 us; speedup vs baseline: 1.3830x; 1.1034x over previous
//
#include <hip/hip_runtime.h>

#define N 2048
#define D 128
#define BB 16

typedef __attribute__((ext_vector_type(8))) short s16x8;   // 8 bf16 = 4 VGPR
typedef __attribute__((ext_vector_type(4))) float f32x4;   // MFMA acc

// Split two fp32 into packed bf16 hi (h) and bf16 lo (l) words.
// hi = truncate-to-bf16(x); lo = truncate-to-bf16(x - hi).  ~2^-16 rel total.
__device__ __forceinline__ void split2(float x0, float x1, unsigned& h, unsigned& l) {
    unsigned b0 = __float_as_uint(x0), b1 = __float_as_uint(x1);
    float r0 = x0 - __uint_as_float(b0 & 0xffff0000u);
    float r1 = x1 - __uint_as_float(b1 & 0xffff0000u);
    h = (b0 >> 16) | (b1 & 0xffff0000u);
    l = (__float_as_uint(r0) >> 16) | (__float_as_uint(r1) & 0xffff0000u);
}

__device__ __forceinline__ s16x8 pack16(uint4 u) {
    union { uint4 a; s16x8 b; } x; x.a = u; return x.b;
}

// ---------------------------------------------------------------------------
// Kernel 0 (fallback only): zero out-region rowsum accumulators.
// ---------------------------------------------------------------------------
__global__ __launch_bounds__(256) void zero_kernel(float4* __restrict__ p, int n4) {
    int i = blockIdx.x * 256 + threadIdx.x;
    const int stride = gridDim.x * 256;
    for (; i < n4; i += stride) p[i] = make_float4(0.f, 0.f, 0.f, 0.f);
}

// ---------------------------------------------------------------------------
// Kernel V: pre-transpose + hi/lo split of V into workspace:
//   Vt_h/Vt_l [b][d=128][n=2048] bf16.
// ---------------------------------------------------------------------------
__global__ __launch_bounds__(256) void vt_kernel(const float* __restrict__ v,
                                                 unsigned short* __restrict__ vth,
                                                 unsigned short* __restrict__ vtl) {
    const int t    = threadIdx.x;
    const int lane = t & 63;
    const int w    = t >> 6;
    const int b    = blockIdx.z;
    const int n0   = blockIdx.x * 32 + w * 8;
    const int d    = blockIdx.y * 64 + lane;
    const float* vp = v + ((size_t)b * N + n0) * D + d;
    float x[8];
    #pragma unroll
    for (int i = 0; i < 8; ++i) x[i] = vp[(size_t)i * D];
    uint4 h, l;
    split2(x[0], x[1], h.x, l.x);
    split2(x[2], x[3], h.y, l.y);
    split2(x[4], x[5], h.z, l.z);
    split2(x[6], x[7], h.w, l.w);
    size_t idx = ((size_t)b * D + d) * N + n0;
    *(uint4*)(vth + idx) = h;
    *(uint4*)(vtl + idx) = l;
}

// ---------------------------------------------------------------------------
// Kernel 1 (fast path): ROWSUM pass, restructured. 64-row blocks, Q staged
// once in LDS (held as register A-frags), K streamed in 64-row chunks with
// register-prefetch double buffering. rs accumulated in registers across all
// chunks, stored non-atomically to out[b][i][0]. MFMA order copied verbatim
// from fused_kernel -> E bit-identical.
// ---------------------------------------------------------------------------
__global__ __launch_bounds__(256, 2) void qs_kernel(const float* __restrict__ q,
                                                    const float* __restrict__ k,
                                                    float* __restrict__ outp) {
    __shared__ unsigned short Qh[64 * 128], Ql[64 * 128];   // 16+16 KB
    __shared__ unsigned short Kh[64 * 128], Kl[64 * 128];   // 16+16 KB
    const int t = threadIdx.x, lane = t & 63, w = t >> 6;
    const int b = blockIdx.y, ib = blockIdx.x * 64;
    const int l15 = lane & 15, l4 = lane >> 4;
    const float* qp = q + ((size_t)b * N + ib) * D;
    const float* kp = k + (size_t)b * N * D;

    // Stage Q once: [64 rows][128 k], hi/lo, 16B-granule XOR swizzle (row&7).
    #pragma unroll
    for (int c = 0; c < 8; ++c) {
        int flat4 = c * 256 + t;
        int row = flat4 >> 5, f4 = flat4 & 31;
        float4 qv = *(const float4*)(qp + (size_t)row * D + f4 * 4);
        uint2 hh, ll;
        split2(qv.x, qv.y, hh.x, ll.x);
        split2(qv.z, qv.w, hh.y, ll.y);
        int idx = row * 128 + (((f4 >> 1) ^ (row & 7)) * 8) + (f4 & 1) * 4;
        *(uint2*)(Qh + idx) = hh;
        *(uint2*)(Ql + idx) = ll;
    }
    __syncthreads();
    // Q A-frags for this wave's 16 rows (row = w*16 + l15).
    s16x8 qh[4], ql[4];
    {
        int row = w * 16 + l15;
        #pragma unroll
        for (int ks = 0; ks < 4; ++ks) {
            int idx = row * 128 + (((ks * 4 + l4) ^ (row & 7)) * 8);
            qh[ks] = *(const s16x8*)(Qh + idx);
            ql[ks] = *(const s16x8*)(Ql + idx);
        }
    }

    float rs[4] = {0.f, 0.f, 0.f, 0.f};

    // Prefetch chunk 0 of K.
    float4 kf[8];
    #pragma unroll
    for (int c = 0; c < 8; ++c) {
        int flat4 = c * 256 + t;
        int row = flat4 >> 5, f4 = flat4 & 31;
        kf[c] = *(const float4*)(kp + (size_t)row * D + f4 * 4);
    }

    for (int jc = 0; jc < 32; ++jc) {
        __syncthreads();   // prev chunk's K reads done (Q buffers unaffected)
        #pragma unroll
        for (int c = 0; c < 8; ++c) {
            int flat4 = c * 256 + t;
            int row = flat4 >> 5, f4 = flat4 & 31;
            uint2 hh, ll;
            split2(kf[c].x, kf[c].y, hh.x, ll.x);
            split2(kf[c].z, kf[c].w, hh.y, ll.y);
            int idx = row * 128 + (((f4 >> 1) ^ (row & 7)) * 8) + (f4 & 1) * 4;
            *(uint2*)(Kh + idx) = hh;
            *(uint2*)(Kl + idx) = ll;
        }
        __syncthreads();
        if (jc < 31) {
            #pragma unroll
            for (int c = 0; c < 8; ++c) {
                int flat4 = c * 256 + t;
                int row = flat4 >> 5, f4 = flat4 & 31;
                kf[c] = *(const float4*)(kp + (size_t)((jc + 1) * 64 + row) * D + f4 * 4);
            }
        }
        // QK^T — identical fragment/accumulation order to fused_kernel.
        f32x4 sacc[4] = {};
        #pragma unroll
        for (int ks = 0; ks < 4; ++ks) {
            s16x8 bh[4], bl[4];
            #pragma unroll
            for (int tj = 0; tj < 4; ++tj) {
                int row = tj * 16 + l15;
                int idx = row * 128 + (((ks * 4 + l4) ^ (row & 7)) * 8);
                bh[tj] = *(const s16x8*)(Kh + idx);
                bl[tj] = *(const s16x8*)(Kl + idx);
            }
            #pragma unroll
            for (int tj = 0; tj < 4; ++tj) {
                sacc[tj] = __builtin_amdgcn_mfma_f32_16x16x32_bf16(qh[ks], bh[tj], sacc[tj], 0, 0, 0);
                sacc[tj] = __builtin_amdgcn_mfma_f32_16x16x32_bf16(qh[ks], bl[tj], sacc[tj], 0, 0, 0);
                sacc[tj] = __builtin_amdgcn_mfma_f32_16x16x32_bf16(ql[ks], bh[tj], sacc[tj], 0, 0, 0);
            }
        }
        #pragma unroll
        for (int r = 0; r < 4; ++r)
            #pragma unroll
            for (int tj = 0; tj < 4; ++tj) rs[r] += __expf(sacc[tj][r]);
    }

    // Reduce over the 16 lanes (cols) and store rowsums (no atomics).
    #pragma unroll
    for (int r = 0; r < 4; ++r) {
        float v0 = rs[r];
        v0 += __shfl_xor(v0, 1);
        v0 += __shfl_xor(v0, 2);
        v0 += __shfl_xor(v0, 4);
        v0 += __shfl_xor(v0, 8);
        if (l15 == 0)
            outp[((size_t)b * N + ib + w * 16 + l4 * 4 + r) * D] = v0;
    }
}

// ---------------------------------------------------------------------------
// Kernel 2 (fused): recompute s = Q@K^T per 64-row tile, P = exp(s)*inv,
// write normalized attn ONCE (full-line float4 stores via Pf readback), and
// accumulate O = P@V via bf16 hi/lo MFMA. attn is never read back.
// ---------------------------------------------------------------------------
__global__ __launch_bounds__(256, 2) void fused_kernel(const float* __restrict__ q,
                                                       const float* __restrict__ k,
                                                       const unsigned short* __restrict__ vth,
                                                       const unsigned short* __restrict__ vtl,
                                                       float* __restrict__ attn,
                                                       float* __restrict__ outp) {
    __shared__ unsigned short Kh[64 * 128], Kl[64 * 128];   // 16+16 KB (K chunk)
    __shared__ unsigned short Vh[128 * 64], Vl[128 * 64];   // 16+16 KB (Vt chunk)
    float* Pf = (float*)Kh;   // aliased P scratch: 4 waves x [16][64] f32 = 16 KB

    const int t = threadIdx.x, lane = t & 63, w = t >> 6;
    const int b = blockIdx.y, ib = blockIdx.x * 64;
    const int l15 = lane & 15, l4 = lane >> 4;
    const float* qp = q + ((size_t)b * N + ib) * D;
    const float* kp = k + (size_t)b * N * D;
    const unsigned short* vhp = vth + (size_t)b * D * N;
    const unsigned short* vlp = vtl + (size_t)b * D * N;
    float* ap = attn + ((size_t)b * N + ib) * N;
    float* op = outp + ((size_t)b * N + ib) * D;

    // inv rowsums for the 4 rows this thread epilogues (C/D row = l4*4+r).
    float inv[4];
    #pragma unroll
    for (int r = 0; r < 4; ++r)
        inv[r] = 1.0f / op[(size_t)(w * 16 + l4 * 4 + r) * D];

    // Q A-frags in registers: Q[w*16+l15][ks*32 + l4*8 .. +7], hi/lo.
    s16x8 qh[4], ql[4];
    {
        const float* qrow = qp + (size_t)(w * 16 + l15) * D;
        #pragma unroll
        for (int ks = 0; ks < 4; ++ks) {
            float4 x0 = *(const float4*)(qrow + ks * 32 + l4 * 8);
            float4 x1 = *(const float4*)(qrow + ks * 32 + l4 * 8 + 4);
            uint4 h, l;
            split2(x0.x, x0.y, h.x, l.x);
            split2(x0.z, x0.w, h.y, l.y);
            split2(x1.x, x1.y, h.z, l.z);
            split2(x1.z, x1.w, h.w, l.w);
            qh[ks] = pack16(h);
            ql[ks] = pack16(l);
        }
    }

    f32x4 oacc[8] = {};

    // Prefetch chunk 0: K rows (fp32) + Vt rows (pre-split bf16).
    float4 kf[8];
    uint4 fh[4], fl[4];
    #pragma unroll
    for (int c = 0; c < 8; ++c) {
        int flat4 = c * 256 + t;
        int row = flat4 >> 5, f4 = flat4 & 31;
        kf[c] = *(const float4*)(kp + (size_t)row * D + f4 * 4);
    }
    #pragma unroll
    for (int c = 0; c < 4; ++c) {
        int flat = c * 256 + t;
        int d = flat >> 3, g = flat & 7;
        fh[c] = *(const uint4*)(vhp + (size_t)d * N + g * 8);
        fl[c] = *(const uint4*)(vlp + (size_t)d * N + g * 8);
    }

    for (int jc = 0; jc < 32; ++jc) {
        __syncthreads();   // (1) prev chunk's PV reads of Vh/Vl and Pf(=Kh) done
        // Stage K chunk [64 j][128 d] hi/lo, 16B-granule XOR swizzle (row&7).
        #pragma unroll
        for (int c = 0; c < 8; ++c) {
            int flat4 = c * 256 + t;
            int row = flat4 >> 5, f4 = flat4 & 31;
            uint2 hh, ll;
            split2(kf[c].x, kf[c].y, hh.x, ll.x);
            split2(kf[c].z, kf[c].w, hh.y, ll.y);
            int idx = row * 128 + (((f4 >> 1) ^ (row & 7)) * 8) + (f4 & 1) * 4;
            *(uint2*)(Kh + idx) = hh;
            *(uint2*)(Kl + idx) = ll;
        }
        // Stage Vt chunk [128 d][64 j] hi/lo.
        #pragma unroll
        for (int c = 0; c < 4; ++c) {
            int flat = c * 256 + t;
            int d = flat >> 3, g = flat & 7;
            int idx = d * 64 + ((g ^ (d & 7)) * 8);
            *(uint4*)(Vh + idx) = fh[c];
            *(uint4*)(Vl + idx) = fl[c];
        }
        __syncthreads();   // (2) staging visible
        // Prefetch chunk jc+1 (latency hides under QK+PV below).
        if (jc < 31) {
            #pragma unroll
            for (int c = 0; c < 8; ++c) {
                int flat4 = c * 256 + t;
                int row = flat4 >> 5, f4 = flat4 & 31;
                kf[c] = *(const float4*)(kp + (size_t)((jc + 1) * 64 + row) * D + f4 * 4);
            }
            #pragma unroll
            for (int c = 0; c < 4; ++c) {
                int flat = c * 256 + t;
                int d = flat >> 3, g = flat & 7;
                fh[c] = *(const uint4*)(vhp + (size_t)d * N + (jc + 1) * 64 + g * 8);
                fl[c] = *(const uint4*)(vlp + (size_t)d * N + (jc + 1) * 64 + g * 8);
            }
        }
        // QK^T: rows w*16..+15 x this chunk's 64 cols (bit-identical to qs).
        f32x4 sacc[4] = {};
        #pragma unroll
        for (int ks = 0; ks < 4; ++ks) {
            s16x8 bh[4], bl[4];
            #pragma unroll
            for (int tj = 0; tj < 4; ++tj) {
                int row = tj * 16 + l15;
                int idx = row * 128 + (((ks * 4 + l4) ^ (row & 7)) * 8);
                bh[tj] = *(const s16x8*)(Kh + idx);
                bl[tj] = *(const s16x8*)(Kl + idx);
            }
            #pragma unroll
            for (int tj = 0; tj < 4; ++tj) {
                sacc[tj] = __builtin_amdgcn_mfma_f32_16x16x32_bf16(qh[ks], bh[tj], sacc[tj], 0, 0, 0);
                sacc[tj] = __builtin_amdgcn_mfma_f32_16x16x32_bf16(qh[ks], bl[tj], sacc[tj], 0, 0, 0);
                sacc[tj] = __builtin_amdgcn_mfma_f32_16x16x32_bf16(ql[ks], bh[tj], sacc[tj], 0, 0, 0);
            }
        }
        __syncthreads();   // (3) all waves done reading Kh/Kl -> Pf alias safe
        // P = exp(s)*inv into per-wave Pf scratch (granule-swizzled).
        float* pw = Pf + w * (16 * 64);
        #pragma unroll
        for (int r = 0; r < 4; ++r) {
            int row = l4 * 4 + r;
            #pragma unroll
            for (int tj = 0; tj < 4; ++tj) {
                float pv = __expf(sacc[tj][r]) * inv[r];
                int gw = (tj * 4 + (l15 >> 2)) ^ ((row & 7) << 1);
                pw[row * 64 + gw * 4 + (l15 & 3)] = pv;
            }
        }
        // attn store via Pf readback: full-128B-line float4 stores.
        // Instr m: lane i -> row (m&1)*8 + (i>>3), granule (i&7) + (m>>1)*8.
        // 8 lanes per row cover 32 contiguous floats (one 128B line).
        #pragma unroll
        for (int m = 0; m < 4; ++m) {
            int row = (m & 1) * 8 + (lane >> 3);
            int lg  = (lane & 7) + (m >> 1) * 8;
            int pg  = lg ^ ((row & 7) << 1);
            float4 pv4 = *(const float4*)(pw + row * 64 + pg * 4);
            *(float4*)(ap + (size_t)(w * 16 + row) * N + jc * 64 + lg * 4) = pv4;
        }
        // PV: A = P rows (wave-local Pf readback), B = Vt.
        #pragma unroll
        for (int ks2 = 0; ks2 < 2; ++ks2) {
            int g0 = (ks2 * 8 + l4 * 2) ^ ((l15 & 7) << 1);   // even; pair stays ordered
            float4 p0 = *(const float4*)(pw + l15 * 64 + g0 * 4);
            float4 p1 = *(const float4*)(pw + l15 * 64 + g0 * 4 + 4);
            uint4 h, l;
            split2(p0.x, p0.y, h.x, l.x);
            split2(p0.z, p0.w, h.y, l.y);
            split2(p1.x, p1.y, h.z, l.z);
            split2(p1.z, p1.w, h.w, l.w);
            s16x8 pah = pack16(h), pal = pack16(l);
            #pragma unroll
            for (int df = 0; df < 8; ++df) {
                int dr = df * 16 + l15;
                int idx = dr * 64 + (((ks2 * 4 + l4) ^ (dr & 7)) * 8);
                s16x8 vbh = *(const s16x8*)(Vh + idx);
                s16x8 vbl = *(const s16x8*)(Vl + idx);
                oacc[df] = __builtin_amdgcn_mfma_f32_16x16x32_bf16(pah, vbh, oacc[df], 0, 0, 0);
                oacc[df] = __builtin_amdgcn_mfma_f32_16x16x32_bf16(pah, vbl, oacc[df], 0, 0, 0);
                oacc[df] = __builtin_amdgcn_mfma_f32_16x16x32_bf16(pal, vbh, oacc[df], 0, 0, 0);
            }
        }
    }

    // Epilogue: write O (overwrites the rowsum scratch at d=0).
    #pragma unroll
    for (int r = 0; r < 4; ++r) {
        int row = w * 16 + l4 * 4 + r;
        #pragma unroll
        for (int df = 0; df < 8; ++df)
            op[(size_t)row * D + df * 16 + l15] = oacc[df][r];
    }
}

// ---------------------------------------------------------------------------
// Fallback path (ws too small): round-2 passing kernels, verbatim.
// ---------------------------------------------------------------------------
__global__ __launch_bounds__(256) void qk_kernel(const float* __restrict__ q,
                                                 const float* __restrict__ k,
                                                 float* __restrict__ attn,
                                                 float* __restrict__ outp) {
    __shared__ unsigned short Qh[128 * 32], Ql[128 * 32];
    __shared__ unsigned short Kh[128 * 32], Kl[128 * 32];
    const int t  = threadIdx.x;
    const int b  = blockIdx.z;
    const int ib = blockIdx.y * 128;
    const int jb = blockIdx.x * 128;
    const float* qp = q + ((size_t)b * N + ib) * D;
    const float* kp = k + ((size_t)b * N + jb) * D;

    const int lane = t & 63;
    const int w    = t >> 6;
    const int wr   = (w >> 1) * 64;
    const int wc   = (w & 1) * 64;
    const int l15  = lane & 15;
    const int l4   = lane >> 4;

    f32x4 acc[4][4] = {};

    for (int ks = 0; ks < 4; ++ks) {
        __syncthreads();
        #pragma unroll
        for (int c = 0; c < 4; ++c) {
            int flat = c * 256 + t;
            int row  = flat >> 3;
            int f4   = flat & 7;
            float4 qv = *(const float4*)(qp + (size_t)row * D + ks * 32 + f4 * 4);
            float4 kv = *(const float4*)(kp + (size_t)row * D + ks * 32 + f4 * 4);
            int idx = row * 32 + (((f4 >> 1) ^ (row & 3)) * 8) + (f4 & 1) * 4;
            uint2 hh, ll;
            split2(qv.x, qv.y, hh.x, ll.x);
            split2(qv.z, qv.w, hh.y, ll.y);
            *(uint2*)(Qh + idx) = hh;
            *(uint2*)(Ql + idx) = ll;
            split2(kv.x, kv.y, hh.x, ll.x);
            split2(kv.z, kv.w, hh.y, ll.y);
            *(uint2*)(Kh + idx) = hh;
            *(uint2*)(Kl + idx) = ll;
        }
        __syncthreads();

        s16x8 ah[4], al[4], bh[4], bl[4];
        #pragma unroll
        for (int ti = 0; ti < 4; ++ti) {
            int row = wr + ti * 16 + l15;
            int idx = row * 32 + ((l4 ^ (row & 3)) * 8);
            ah[ti] = *(const s16x8*)(Qh + idx);
            al[ti] = *(const s16x8*)(Ql + idx);
        }
        #pragma unroll
        for (int tj = 0; tj < 4; ++tj) {
            int row = wc + tj * 16 + l15;
            int idx = row * 32 + ((l4 ^ (row & 3)) * 8);
            bh[tj] = *(const s16x8*)(Kh + idx);
            bl[tj] = *(const s16x8*)(Kl + idx);
        }
        #pragma unroll
        for (int ti = 0; ti < 4; ++ti)
            #pragma unroll
            for (int tj = 0; tj < 4; ++tj) {
                acc[ti][tj] = __builtin_amdgcn_mfma_f32_16x16x32_bf16(ah[ti], bh[tj], acc[ti][tj], 0, 0, 0);
                acc[ti][tj] = __builtin_amdgcn_mfma_f32_16x16x32_bf16(ah[ti], bl[tj], acc[ti][tj], 0, 0, 0);
                acc[ti][tj] = __builtin_amdgcn_mfma_f32_16x16x32_bf16(al[ti], bh[tj], acc[ti][tj], 0, 0, 0);
            }
    }

    #pragma unroll
    for (int ti = 0; ti < 4; ++ti) {
        #pragma unroll
        for (int r = 0; r < 4; ++r) {
            int row = ib + wr + ti * 16 + l4 * 4 + r;
            float* arow = attn + ((size_t)b * N + row) * N + jb + wc;
            float rs = 0.f;
            #pragma unroll
            for (int tj = 0; tj < 4; ++tj) {
                float e = __expf(acc[ti][tj][r]);
                arow[tj * 16 + l15] = e;
                rs += e;
            }
            rs += __shfl_xor(rs, 1);
            rs += __shfl_xor(rs, 2);
            rs += __shfl_xor(rs, 4);
            rs += __shfl_xor(rs, 8);
            if (l15 == 0) atomicAdd(outp + ((size_t)b * N + row) * D, rs);
        }
    }
}

__global__ __launch_bounds__(256) void pv_fb_kernel(const float* __restrict__ v,
                                                    float* __restrict__ attn,
                                                    float* __restrict__ outp) {
    __shared__ unsigned short Ph[64 * 64], Pl[64 * 64];
    __shared__ unsigned short Vth[128 * 64], Vtl[128 * 64];
    __shared__ float invs[64];
    const int t  = threadIdx.x;
    const int b  = blockIdx.y;
    const int ib = blockIdx.x * 64;
    float* ap       = attn + ((size_t)b * N + ib) * N;
    const float* vp = v + (size_t)b * N * D;
    float* op       = outp + ((size_t)b * N + ib) * D;

    if (t < 64) invs[t] = 1.0f / op[(size_t)t * D];

    const int lane = t & 63;
    const int w    = t >> 6;
    const int rg   = (w >> 1) * 32;
    const int dg   = (w & 1) * 64;
    const int l15  = lane & 15;
    const int l4   = lane >> 4;

    f32x4 acc[2][4] = {};

    float4 pe[4], va[4], vb[4];
    #pragma unroll
    for (int c = 0; c < 4; ++c) {
        int flat = c * 256 + t;
        pe[c] = *(const float4*)(ap + (size_t)(flat >> 4) * N + (flat & 15) * 4);
        int jp = flat >> 5, d4 = flat & 31;
        va[c] = *(const float4*)(vp + (size_t)(jp * 2) * D + d4 * 4);
        vb[c] = *(const float4*)(vp + (size_t)(jp * 2 + 1) * D + d4 * 4);
    }

    for (int jc = 0; jc < 32; ++jc) {
        __syncthreads();
        #pragma unroll
        for (int c = 0; c < 4; ++c) {
            int flat = c * 256 + t;
            int row = flat >> 4, j4 = flat & 15;
            float iv = invs[row];
            float4 p4;
            p4.x = pe[c].x * iv; p4.y = pe[c].y * iv;
            p4.z = pe[c].z * iv; p4.w = pe[c].w * iv;
            *(float4*)(ap + (size_t)row * N + jc * 64 + j4 * 4) = p4;
            uint2 hh, ll;
            split2(p4.x, p4.y, hh.x, ll.x);
            split2(p4.z, p4.w, hh.y, ll.y);
            int idx = row * 64 + (((j4 >> 1) ^ (row & 7)) * 8) + (j4 & 1) * 4;
            *(uint2*)(Ph + idx) = hh;
            *(uint2*)(Pl + idx) = ll;
        }
        #pragma unroll
        for (int c = 0; c < 4; ++c) {
            int flat = c * 256 + t;
            int jp = flat >> 5, d4 = flat & 31;
            int j = jp * 2;
            float4 v0 = va[c], v1 = vb[c];
            #pragma unroll
            for (int e = 0; e < 4; ++e) {
                float x0 = (&v0.x)[e], x1 = (&v1.x)[e];
                unsigned h, l;
                split2(x0, x1, h, l);
                int d = d4 * 4 + e;
                int idx = d * 64 + (((j >> 3) ^ (d & 7)) * 8) + (j & 7);
                *(unsigned*)(Vth + idx) = h;
                *(unsigned*)(Vtl + idx) = l;
            }
        }
        __syncthreads();
        if (jc < 31) {
            #pragma unroll
            for (int c = 0; c < 4; ++c) {
                int flat = c * 256 + t;
                pe[c] = *(const float4*)(ap + (size_t)(flat >> 4) * N + (jc + 1) * 64 + (flat & 15) * 4);
                int jp = flat >> 5, d4 = flat & 31;
                va[c] = *(const float4*)(vp + (size_t)((jc + 1) * 64 + jp * 2) * D + d4 * 4);
                vb[c] = *(const float4*)(vp + (size_t)((jc + 1) * 64 + jp * 2 + 1) * D + d4 * 4);
            }
        }
        #pragma unroll
        for (int ksj = 0; ksj < 2; ++ksj) {
            s16x8 pah[2], pal[2], bh[4], bl[4];
            #pragma unroll
            for (int ti = 0; ti < 2; ++ti) {
                int row = rg + ti * 16 + l15;
                int idx = row * 64 + (((ksj * 4 + l4) ^ (row & 7)) * 8);
                pah[ti] = *(const s16x8*)(Ph + idx);
                pal[ti] = *(const s16x8*)(Pl + idx);
            }
            #pragma unroll
            for (int tj = 0; tj < 4; ++tj) {
                int d = dg + tj * 16 + l15;
                int idx = d * 64 + (((ksj * 4 + l4) ^ (d & 7)) * 8);
                bh[tj] = *(const s16x8*)(Vth + idx);
                bl[tj] = *(const s16x8*)(Vtl + idx);
            }
            #pragma unroll
            for (int ti = 0; ti < 2; ++ti)
                #pragma unroll
                for (int tj = 0; tj < 4; ++tj) {
                    acc[ti][tj] = __builtin_amdgcn_mfma_f32_16x16x32_bf16(pah[ti], bh[tj], acc[ti][tj], 0, 0, 0);
                    acc[ti][tj] = __builtin_amdgcn_mfma_f32_16x16x32_bf16(pah[ti], bl[tj], acc[ti][tj], 0, 0, 0);
                    acc[ti][tj] = __builtin_amdgcn_mfma_f32_16x16x32_bf16(pal[ti], bh[tj], acc[ti][tj], 0, 0, 0);
                }
        }
    }

    #pragma unroll
    for (int ti = 0; ti < 2; ++ti)
        #pragma unroll
        for (int r = 0; r < 4; ++r) {
            int row = rg + ti * 16 + l4 * 4 + r;
            #pragma unroll
            for (int tj = 0; tj < 4; ++tj)
                op[(size_t)row * D + dg + tj * 16 + l15] = acc[ti][tj][r];
        }
}

extern "C" void kernel_launch(void* const* d_in, const int* in_sizes, int n_in,
                              void* d_out, int out_size, void* d_ws, size_t ws_size,
                              hipStream_t stream) {
    const float* q = (const float*)d_in[0];
    const float* k = (const float*)d_in[1];
    const float* v = (const float*)d_in[2];
    float* out  = (float*)d_out;                    // [16,2048,128]
    float* attn = out + (size_t)BB * N * D;         // [16,2048,2048]

    const size_t vt_elems = (size_t)BB * D * N;     // 4,194,304
    const bool use_ws = ws_size >= vt_elems * 2 * sizeof(unsigned short);  // 16.78 MB

    if (use_ws) {
        unsigned short* vth = (unsigned short*)d_ws;
        unsigned short* vtl = vth + vt_elems;
        vt_kernel<<<dim3(N / 32, 2, BB), 256, 0, stream>>>(v, vth, vtl);
        qs_kernel<<<dim3(N / 64, BB), 256, 0, stream>>>(q, k, out);
        fused_kernel<<<dim3(N / 64, BB), 256, 0, stream>>>(q, k, vth, vtl, attn, out);
    } else {
        zero_kernel<<<1024, 256, 0, stream>>>((float4*)out, BB * N * D / 4);
        qk_kernel<<<dim3(N / 128, N / 128, BB), 256, 0, stream>>>(q, k, attn, out);
        pv_fb_kernel<<<dim3(N / 64, BB), 256, 0, stream>>>(v, attn, out);
    }
}

// Round 6
// 494.103 us; speedup vs baseline: 1.4411x; 1.0420x over previous
//
#include <hip/hip_runtime.h>

#define N 2048
#define D 128
#define BB 16
#define PFS 68   // Pf scratch row stride (floats): 68 breaks bank aliasing

typedef __attribute__((ext_vector_type(8))) short s16x8;   // 8 bf16 = 4 VGPR
typedef __attribute__((ext_vector_type(4))) float f32x4;   // MFMA acc

// Split two fp32 into packed bf16 hi (h) and bf16 lo (l) words.
// hi = truncate-to-bf16(x); lo = truncate-to-bf16(x - hi).  ~2^-16 rel total.
__device__ __forceinline__ void split2(float x0, float x1, unsigned& h, unsigned& l) {
    unsigned b0 = __float_as_uint(x0), b1 = __float_as_uint(x1);
    float r0 = x0 - __uint_as_float(b0 & 0xffff0000u);
    float r1 = x1 - __uint_as_float(b1 & 0xffff0000u);
    h = (b0 >> 16) | (b1 & 0xffff0000u);
    l = (__float_as_uint(r0) >> 16) | (__float_as_uint(r1) & 0xffff0000u);
}

__device__ __forceinline__ s16x8 pack16(uint4 u) {
    union { uint4 a; s16x8 b; } x; x.a = u; return x.b;
}

// ---------------------------------------------------------------------------
// Kernel 0 (fallback only): zero out-region rowsum accumulators.
// ---------------------------------------------------------------------------
__global__ __launch_bounds__(256) void zero_kernel(float4* __restrict__ p, int n4) {
    int i = blockIdx.x * 256 + threadIdx.x;
    const int stride = gridDim.x * 256;
    for (; i < n4; i += stride) p[i] = make_float4(0.f, 0.f, 0.f, 0.f);
}

// ---------------------------------------------------------------------------
// Kernel V: pre-transpose + hi/lo split of V into workspace:
//   Vt_h/Vt_l [b][d=128][n=2048] bf16.
// ---------------------------------------------------------------------------
__global__ __launch_bounds__(256) void vt_kernel(const float* __restrict__ v,
                                                 unsigned short* __restrict__ vth,
                                                 unsigned short* __restrict__ vtl) {
    const int t    = threadIdx.x;
    const int lane = t & 63;
    const int w    = t >> 6;
    const int b    = blockIdx.z;
    const int n0   = blockIdx.x * 32 + w * 8;
    const int d    = blockIdx.y * 64 + lane;
    const float* vp = v + ((size_t)b * N + n0) * D + d;
    float x[8];
    #pragma unroll
    for (int i = 0; i < 8; ++i) x[i] = vp[(size_t)i * D];
    uint4 h, l;
    split2(x[0], x[1], h.x, l.x);
    split2(x[2], x[3], h.y, l.y);
    split2(x[4], x[5], h.z, l.z);
    split2(x[6], x[7], h.w, l.w);
    size_t idx = ((size_t)b * D + d) * N + n0;
    *(uint4*)(vth + idx) = h;
    *(uint4*)(vtl + idx) = l;
}

// ---------------------------------------------------------------------------
// Kernel 1 (fast path): ROWSUM pass. 64-row blocks, Q staged once in LDS,
// K streamed in 64-row chunks with register-prefetch double buffering.
// XCD-aware 1D grid: xcd = wgid&7 owns a contiguous chunk (2 batches), so
// its K stream stays L2-resident. MFMA order identical to fused_kernel.
// ---------------------------------------------------------------------------
__global__ __launch_bounds__(256, 2) void qs_kernel(const float* __restrict__ q,
                                                    const float* __restrict__ k,
                                                    float* __restrict__ outp) {
    __shared__ unsigned short Qh[64 * 128], Ql[64 * 128];   // 16+16 KB
    __shared__ unsigned short Kh[64 * 128], Kl[64 * 128];   // 16+16 KB
    const int t = threadIdx.x, lane = t & 63, w = t >> 6;
    // XCD swizzle: wgid&7 -> XCD (round-robin); give each XCD 64 contiguous tiles.
    const int swz = (blockIdx.x & 7) * 64 + (blockIdx.x >> 3);
    const int b = swz >> 5, ib = (swz & 31) * 64;
    const int l15 = lane & 15, l4 = lane >> 4;
    const float* qp = q + ((size_t)b * N + ib) * D;
    const float* kp = k + (size_t)b * N * D;

    // Stage Q once: [64 rows][128 k], hi/lo, 16B-granule XOR swizzle (row&7).
    #pragma unroll
    for (int c = 0; c < 8; ++c) {
        int flat4 = c * 256 + t;
        int row = flat4 >> 5, f4 = flat4 & 31;
        float4 qv = *(const float4*)(qp + (size_t)row * D + f4 * 4);
        uint2 hh, ll;
        split2(qv.x, qv.y, hh.x, ll.x);
        split2(qv.z, qv.w, hh.y, ll.y);
        int idx = row * 128 + (((f4 >> 1) ^ (row & 7)) * 8) + (f4 & 1) * 4;
        *(uint2*)(Qh + idx) = hh;
        *(uint2*)(Ql + idx) = ll;
    }
    __syncthreads();
    // Q A-frags for this wave's 16 rows (row = w*16 + l15).
    s16x8 qh[4], ql[4];
    {
        int row = w * 16 + l15;
        #pragma unroll
        for (int ks = 0; ks < 4; ++ks) {
            int idx = row * 128 + (((ks * 4 + l4) ^ (row & 7)) * 8);
            qh[ks] = *(const s16x8*)(Qh + idx);
            ql[ks] = *(const s16x8*)(Ql + idx);
        }
    }

    float rs[4] = {0.f, 0.f, 0.f, 0.f};

    // Prefetch chunk 0 of K.
    float4 kf[8];
    #pragma unroll
    for (int c = 0; c < 8; ++c) {
        int flat4 = c * 256 + t;
        int row = flat4 >> 5, f4 = flat4 & 31;
        kf[c] = *(const float4*)(kp + (size_t)row * D + f4 * 4);
    }

    for (int jc = 0; jc < 32; ++jc) {
        __syncthreads();   // prev chunk's K reads done (Q buffers unaffected)
        #pragma unroll
        for (int c = 0; c < 8; ++c) {
            int flat4 = c * 256 + t;
            int row = flat4 >> 5, f4 = flat4 & 31;
            uint2 hh, ll;
            split2(kf[c].x, kf[c].y, hh.x, ll.x);
            split2(kf[c].z, kf[c].w, hh.y, ll.y);
            int idx = row * 128 + (((f4 >> 1) ^ (row & 7)) * 8) + (f4 & 1) * 4;
            *(uint2*)(Kh + idx) = hh;
            *(uint2*)(Kl + idx) = ll;
        }
        __syncthreads();
        if (jc < 31) {
            #pragma unroll
            for (int c = 0; c < 8; ++c) {
                int flat4 = c * 256 + t;
                int row = flat4 >> 5, f4 = flat4 & 31;
                kf[c] = *(const float4*)(kp + (size_t)((jc + 1) * 64 + row) * D + f4 * 4);
            }
        }
        // QK^T — identical fragment/accumulation order to fused_kernel.
        f32x4 sacc[4] = {};
        #pragma unroll
        for (int ks = 0; ks < 4; ++ks) {
            s16x8 bh[4], bl[4];
            #pragma unroll
            for (int tj = 0; tj < 4; ++tj) {
                int row = tj * 16 + l15;
                int idx = row * 128 + (((ks * 4 + l4) ^ (row & 7)) * 8);
                bh[tj] = *(const s16x8*)(Kh + idx);
                bl[tj] = *(const s16x8*)(Kl + idx);
            }
            #pragma unroll
            for (int tj = 0; tj < 4; ++tj) {
                sacc[tj] = __builtin_amdgcn_mfma_f32_16x16x32_bf16(qh[ks], bh[tj], sacc[tj], 0, 0, 0);
                sacc[tj] = __builtin_amdgcn_mfma_f32_16x16x32_bf16(qh[ks], bl[tj], sacc[tj], 0, 0, 0);
                sacc[tj] = __builtin_amdgcn_mfma_f32_16x16x32_bf16(ql[ks], bh[tj], sacc[tj], 0, 0, 0);
            }
        }
        #pragma unroll
        for (int r = 0; r < 4; ++r)
            #pragma unroll
            for (int tj = 0; tj < 4; ++tj) rs[r] += __expf(sacc[tj][r]);
    }

    // Reduce over the 16 lanes (cols) and store rowsums (no atomics).
    #pragma unroll
    for (int r = 0; r < 4; ++r) {
        float v0 = rs[r];
        v0 += __shfl_xor(v0, 1);
        v0 += __shfl_xor(v0, 2);
        v0 += __shfl_xor(v0, 4);
        v0 += __shfl_xor(v0, 8);
        if (l15 == 0)
            outp[((size_t)b * N + ib + w * 16 + l4 * 4 + r) * D] = v0;
    }
}

// ---------------------------------------------------------------------------
// Kernel 2 (fused): recompute s = Q@K^T per 64-row tile, P = exp(s)*inv,
// write normalized attn ONCE (nontemporal full-line float4 stores), and
// accumulate O = P@V. XCD-swizzled grid keeps K+Vt (4 MB/2 batches) resident
// in the XCD's L2; nt stores keep the attn stream from thrashing it.
// ---------------------------------------------------------------------------
__global__ __launch_bounds__(256, 2) void fused_kernel(const float* __restrict__ q,
                                                       const float* __restrict__ k,
                                                       const unsigned short* __restrict__ vth,
                                                       const unsigned short* __restrict__ vtl,
                                                       float* __restrict__ attn,
                                                       float* __restrict__ outp) {
    __shared__ unsigned short KBuf[2 * 64 * 128];           // Kh|Kl, 32 KB contiguous
    __shared__ unsigned short Vh[128 * 64], Vl[128 * 64];   // 16+16 KB (Vt chunk)
    unsigned short* Kh = KBuf;
    unsigned short* Kl = KBuf + 64 * 128;
    float* Pf = (float*)KBuf;   // aliased P scratch: 4 waves x [16][PFS] f32 = 17.4 KB

    const int t = threadIdx.x, lane = t & 63, w = t >> 6;
    const int swz = (blockIdx.x & 7) * 64 + (blockIdx.x >> 3);
    const int b = swz >> 5, ib = (swz & 31) * 64;
    const int l15 = lane & 15, l4 = lane >> 4;
    const float* qp = q + ((size_t)b * N + ib) * D;
    const float* kp = k + (size_t)b * N * D;
    const unsigned short* vhp = vth + (size_t)b * D * N;
    const unsigned short* vlp = vtl + (size_t)b * D * N;
    float* ap = attn + ((size_t)b * N + ib) * N;
    float* op = outp + ((size_t)b * N + ib) * D;

    // inv rowsums for the 4 rows this thread epilogues (C/D row = l4*4+r).
    float inv[4];
    #pragma unroll
    for (int r = 0; r < 4; ++r)
        inv[r] = 1.0f / op[(size_t)(w * 16 + l4 * 4 + r) * D];

    // Q A-frags in registers: Q[w*16+l15][ks*32 + l4*8 .. +7], hi/lo.
    s16x8 qh[4], ql[4];
    {
        const float* qrow = qp + (size_t)(w * 16 + l15) * D;
        #pragma unroll
        for (int ks = 0; ks < 4; ++ks) {
            float4 x0 = *(const float4*)(qrow + ks * 32 + l4 * 8);
            float4 x1 = *(const float4*)(qrow + ks * 32 + l4 * 8 + 4);
            uint4 h, l;
            split2(x0.x, x0.y, h.x, l.x);
            split2(x0.z, x0.w, h.y, l.y);
            split2(x1.x, x1.y, h.z, l.z);
            split2(x1.z, x1.w, h.w, l.w);
            qh[ks] = pack16(h);
            ql[ks] = pack16(l);
        }
    }

    f32x4 oacc[8] = {};

    // Prefetch chunk 0: K rows (fp32) + Vt rows (pre-split bf16).
    float4 kf[8];
    uint4 fh[4], fl[4];
    #pragma unroll
    for (int c = 0; c < 8; ++c) {
        int flat4 = c * 256 + t;
        int row = flat4 >> 5, f4 = flat4 & 31;
        kf[c] = *(const float4*)(kp + (size_t)row * D + f4 * 4);
    }
    #pragma unroll
    for (int c = 0; c < 4; ++c) {
        int flat = c * 256 + t;
        int d = flat >> 3, g = flat & 7;
        fh[c] = *(const uint4*)(vhp + (size_t)d * N + g * 8);
        fl[c] = *(const uint4*)(vlp + (size_t)d * N + g * 8);
    }

    for (int jc = 0; jc < 32; ++jc) {
        __syncthreads();   // (1) prev chunk's PV reads of Vh/Vl and Pf(=KBuf) done
        // Stage K chunk [64 j][128 d] hi/lo, 16B-granule XOR swizzle (row&7).
        #pragma unroll
        for (int c = 0; c < 8; ++c) {
            int flat4 = c * 256 + t;
            int row = flat4 >> 5, f4 = flat4 & 31;
            uint2 hh, ll;
            split2(kf[c].x, kf[c].y, hh.x, ll.x);
            split2(kf[c].z, kf[c].w, hh.y, ll.y);
            int idx = row * 128 + (((f4 >> 1) ^ (row & 7)) * 8) + (f4 & 1) * 4;
            *(uint2*)(Kh + idx) = hh;
            *(uint2*)(Kl + idx) = ll;
        }
        // Stage Vt chunk [128 d][64 j] hi/lo.
        #pragma unroll
        for (int c = 0; c < 4; ++c) {
            int flat = c * 256 + t;
            int d = flat >> 3, g = flat & 7;
            int idx = d * 64 + ((g ^ (d & 7)) * 8);
            *(uint4*)(Vh + idx) = fh[c];
            *(uint4*)(Vl + idx) = fl[c];
        }
        __syncthreads();   // (2) staging visible
        // Prefetch chunk jc+1 (latency hides under QK+PV below).
        if (jc < 31) {
            #pragma unroll
            for (int c = 0; c < 8; ++c) {
                int flat4 = c * 256 + t;
                int row = flat4 >> 5, f4 = flat4 & 31;
                kf[c] = *(const float4*)(kp + (size_t)((jc + 1) * 64 + row) * D + f4 * 4);
            }
            #pragma unroll
            for (int c = 0; c < 4; ++c) {
                int flat = c * 256 + t;
                int d = flat >> 3, g = flat & 7;
                fh[c] = *(const uint4*)(vhp + (size_t)d * N + (jc + 1) * 64 + g * 8);
                fl[c] = *(const uint4*)(vlp + (size_t)d * N + (jc + 1) * 64 + g * 8);
            }
        }
        // QK^T: rows w*16..+15 x this chunk's 64 cols (bit-identical to qs).
        f32x4 sacc[4] = {};
        #pragma unroll
        for (int ks = 0; ks < 4; ++ks) {
            s16x8 bh[4], bl[4];
            #pragma unroll
            for (int tj = 0; tj < 4; ++tj) {
                int row = tj * 16 + l15;
                int idx = row * 128 + (((ks * 4 + l4) ^ (row & 7)) * 8);
                bh[tj] = *(const s16x8*)(Kh + idx);
                bl[tj] = *(const s16x8*)(Kl + idx);
            }
            #pragma unroll
            for (int tj = 0; tj < 4; ++tj) {
                sacc[tj] = __builtin_amdgcn_mfma_f32_16x16x32_bf16(qh[ks], bh[tj], sacc[tj], 0, 0, 0);
                sacc[tj] = __builtin_amdgcn_mfma_f32_16x16x32_bf16(qh[ks], bl[tj], sacc[tj], 0, 0, 0);
                sacc[tj] = __builtin_amdgcn_mfma_f32_16x16x32_bf16(ql[ks], bh[tj], sacc[tj], 0, 0, 0);
            }
        }
        __syncthreads();   // (3) all waves done reading Kh/Kl -> Pf alias safe
        // P = exp(s)*inv into per-wave Pf scratch (granule-swizzled, stride 68).
        float* pw = Pf + w * (16 * PFS);
        #pragma unroll
        for (int r = 0; r < 4; ++r) {
            int row = l4 * 4 + r;
            #pragma unroll
            for (int tj = 0; tj < 4; ++tj) {
                float pv = __expf(sacc[tj][r]) * inv[r];
                int gw = (tj * 4 + (l15 >> 2)) ^ ((row & 7) << 1);
                pw[row * PFS + gw * 4 + (l15 & 3)] = pv;
            }
        }
        // attn store via Pf readback: full-128B-line nontemporal float4 stores.
        #pragma unroll
        for (int m = 0; m < 4; ++m) {
            int row = (m & 1) * 8 + (lane >> 3);
            int lg  = (lane & 7) + (m >> 1) * 8;
            int pg  = lg ^ ((row & 7) << 1);
            f32x4 pv4 = *(const f32x4*)(pw + row * PFS + pg * 4);
            __builtin_nontemporal_store(pv4,
                (f32x4*)(ap + (size_t)(w * 16 + row) * N + jc * 64 + lg * 4));
        }
        // PV: A = P rows (wave-local Pf readback), B = Vt.
        #pragma unroll
        for (int ks2 = 0; ks2 < 2; ++ks2) {
            int g0 = (ks2 * 8 + l4 * 2) ^ ((l15 & 7) << 1);   // even; pair stays ordered
            float4 p0 = *(const float4*)(pw + l15 * PFS + g0 * 4);
            float4 p1 = *(const float4*)(pw + l15 * PFS + g0 * 4 + 4);
            uint4 h, l;
            split2(p0.x, p0.y, h.x, l.x);
            split2(p0.z, p0.w, h.y, l.y);
            split2(p1.x, p1.y, h.z, l.z);
            split2(p1.z, p1.w, h.w, l.w);
            s16x8 pah = pack16(h), pal = pack16(l);
            #pragma unroll
            for (int df = 0; df < 8; ++df) {
                int dr = df * 16 + l15;
                int idx = dr * 64 + (((ks2 * 4 + l4) ^ (dr & 7)) * 8);
                s16x8 vbh = *(const s16x8*)(Vh + idx);
                s16x8 vbl = *(const s16x8*)(Vl + idx);
                oacc[df] = __builtin_amdgcn_mfma_f32_16x16x32_bf16(pah, vbh, oacc[df], 0, 0, 0);
                oacc[df] = __builtin_amdgcn_mfma_f32_16x16x32_bf16(pah, vbl, oacc[df], 0, 0, 0);
                oacc[df] = __builtin_amdgcn_mfma_f32_16x16x32_bf16(pal, vbh, oacc[df], 0, 0, 0);
            }
        }
    }

    // Epilogue: write O nontemporally (overwrites the rowsum scratch at d=0).
    #pragma unroll
    for (int r = 0; r < 4; ++r) {
        int row = w * 16 + l4 * 4 + r;
        #pragma unroll
        for (int df = 0; df < 8; ++df)
            __builtin_nontemporal_store(oacc[df][r],
                op + (size_t)row * D + df * 16 + l15);
    }
}

// ---------------------------------------------------------------------------
// Fallback path (ws too small): round-2 passing kernels, verbatim.
// ---------------------------------------------------------------------------
__global__ __launch_bounds__(256) void qk_kernel(const float* __restrict__ q,
                                                 const float* __restrict__ k,
                                                 float* __restrict__ attn,
                                                 float* __restrict__ outp) {
    __shared__ unsigned short Qh[128 * 32], Ql[128 * 32];
    __shared__ unsigned short Kh[128 * 32], Kl[128 * 32];
    const int t  = threadIdx.x;
    const int b  = blockIdx.z;
    const int ib = blockIdx.y * 128;
    const int jb = blockIdx.x * 128;
    const float* qp = q + ((size_t)b * N + ib) * D;
    const float* kp = k + ((size_t)b * N + jb) * D;

    const int lane = t & 63;
    const int w    = t >> 6;
    const int wr   = (w >> 1) * 64;
    const int wc   = (w & 1) * 64;
    const int l15  = lane & 15;
    const int l4   = lane >> 4;

    f32x4 acc[4][4] = {};

    for (int ks = 0; ks < 4; ++ks) {
        __syncthreads();
        #pragma unroll
        for (int c = 0; c < 4; ++c) {
            int flat = c * 256 + t;
            int row  = flat >> 3;
            int f4   = flat & 7;
            float4 qv = *(const float4*)(qp + (size_t)row * D + ks * 32 + f4 * 4);
            float4 kv = *(const float4*)(kp + (size_t)row * D + ks * 32 + f4 * 4);
            int idx = row * 32 + (((f4 >> 1) ^ (row & 3)) * 8) + (f4 & 1) * 4;
            uint2 hh, ll;
            split2(qv.x, qv.y, hh.x, ll.x);
            split2(qv.z, qv.w, hh.y, ll.y);
            *(uint2*)(Qh + idx) = hh;
            *(uint2*)(Ql + idx) = ll;
            split2(kv.x, kv.y, hh.x, ll.x);
            split2(kv.z, kv.w, hh.y, ll.y);
            *(uint2*)(Kh + idx) = hh;
            *(uint2*)(Kl + idx) = ll;
        }
        __syncthreads();

        s16x8 ah[4], al[4], bh[4], bl[4];
        #pragma unroll
        for (int ti = 0; ti < 4; ++ti) {
            int row = wr + ti * 16 + l15;
            int idx = row * 32 + ((l4 ^ (row & 3)) * 8);
            ah[ti] = *(const s16x8*)(Qh + idx);
            al[ti] = *(const s16x8*)(Ql + idx);
        }
        #pragma unroll
        for (int tj = 0; tj < 4; ++tj) {
            int row = wc + tj * 16 + l15;
            int idx = row * 32 + ((l4 ^ (row & 3)) * 8);
            bh[tj] = *(const s16x8*)(Kh + idx);
            bl[tj] = *(const s16x8*)(Kl + idx);
        }
        #pragma unroll
        for (int ti = 0; ti < 4; ++ti)
            #pragma unroll
            for (int tj = 0; tj < 4; ++tj) {
                acc[ti][tj] = __builtin_amdgcn_mfma_f32_16x16x32_bf16(ah[ti], bh[tj], acc[ti][tj], 0, 0, 0);
                acc[ti][tj] = __builtin_amdgcn_mfma_f32_16x16x32_bf16(ah[ti], bl[tj], acc[ti][tj], 0, 0, 0);
                acc[ti][tj] = __builtin_amdgcn_mfma_f32_16x16x32_bf16(al[ti], bh[tj], acc[ti][tj], 0, 0, 0);
            }
    }

    #pragma unroll
    for (int ti = 0; ti < 4; ++ti) {
        #pragma unroll
        for (int r = 0; r < 4; ++r) {
            int row = ib + wr + ti * 16 + l4 * 4 + r;
            float* arow = attn + ((size_t)b * N + row) * N + jb + wc;
            float rs = 0.f;
            #pragma unroll
            for (int tj = 0; tj < 4; ++tj) {
                float e = __expf(acc[ti][tj][r]);
                arow[tj * 16 + l15] = e;
                rs += e;
            }
            rs += __shfl_xor(rs, 1);
            rs += __shfl_xor(rs, 2);
            rs += __shfl_xor(rs, 4);
            rs += __shfl_xor(rs, 8);
            if (l15 == 0) atomicAdd(outp + ((size_t)b * N + row) * D, rs);
        }
    }
}

__global__ __launch_bounds__(256) void pv_fb_kernel(const float* __restrict__ v,
                                                    float* __restrict__ attn,
                                                    float* __restrict__ outp) {
    __shared__ unsigned short Ph[64 * 64], Pl[64 * 64];
    __shared__ unsigned short Vth[128 * 64], Vtl[128 * 64];
    __shared__ float invs[64];
    const int t  = threadIdx.x;
    const int b  = blockIdx.y;
    const int ib = blockIdx.x * 64;
    float* ap       = attn + ((size_t)b * N + ib) * N;
    const float* vp = v + (size_t)b * N * D;
    float* op       = outp + ((size_t)b * N + ib) * D;

    if (t < 64) invs[t] = 1.0f / op[(size_t)t * D];

    const int lane = t & 63;
    const int w    = t >> 6;
    const int rg   = (w >> 1) * 32;
    const int dg   = (w & 1) * 64;
    const int l15  = lane & 15;
    const int l4   = lane >> 4;

    f32x4 acc[2][4] = {};

    float4 pe[4], va[4], vb[4];
    #pragma unroll
    for (int c = 0; c < 4; ++c) {
        int flat = c * 256 + t;
        pe[c] = *(const float4*)(ap + (size_t)(flat >> 4) * N + (flat & 15) * 4);
        int jp = flat >> 5, d4 = flat & 31;
        va[c] = *(const float4*)(vp + (size_t)(jp * 2) * D + d4 * 4);
        vb[c] = *(const float4*)(vp + (size_t)(jp * 2 + 1) * D + d4 * 4);
    }

    for (int jc = 0; jc < 32; ++jc) {
        __syncthreads();
        #pragma unroll
        for (int c = 0; c < 4; ++c) {
            int flat = c * 256 + t;
            int row = flat >> 4, j4 = flat & 15;
            float iv = invs[row];
            float4 p4;
            p4.x = pe[c].x * iv; p4.y = pe[c].y * iv;
            p4.z = pe[c].z * iv; p4.w = pe[c].w * iv;
            *(float4*)(ap + (size_t)row * N + jc * 64 + j4 * 4) = p4;
            uint2 hh, ll;
            split2(p4.x, p4.y, hh.x, ll.x);
            split2(p4.z, p4.w, hh.y, ll.y);
            int idx = row * 64 + (((j4 >> 1) ^ (row & 7)) * 8) + (j4 & 1) * 4;
            *(uint2*)(Ph + idx) = hh;
            *(uint2*)(Pl + idx) = ll;
        }
        #pragma unroll
        for (int c = 0; c < 4; ++c) {
            int flat = c * 256 + t;
            int jp = flat >> 5, d4 = flat & 31;
            int j = jp * 2;
            float4 v0 = va[c], v1 = vb[c];
            #pragma unroll
            for (int e = 0; e < 4; ++e) {
                float x0 = (&v0.x)[e], x1 = (&v1.x)[e];
                unsigned h, l;
                split2(x0, x1, h, l);
                int d = d4 * 4 + e;
                int idx = d * 64 + (((j >> 3) ^ (d & 7)) * 8) + (j & 7);
                *(unsigned*)(Vth + idx) = h;
                *(unsigned*)(Vtl + idx) = l;
            }
        }
        __syncthreads();
        if (jc < 31) {
            #pragma unroll
            for (int c = 0; c < 4; ++c) {
                int flat = c * 256 + t;
                pe[c] = *(const float4*)(ap + (size_t)(flat >> 4) * N + (jc + 1) * 64 + (flat & 15) * 4);
                int jp = flat >> 5, d4 = flat & 31;
                va[c] = *(const float4*)(vp + (size_t)((jc + 1) * 64 + jp * 2) * D + d4 * 4);
                vb[c] = *(const float4*)(vp + (size_t)((jc + 1) * 64 + jp * 2 + 1) * D + d4 * 4);
            }
        }
        #pragma unroll
        for (int ksj = 0; ksj < 2; ++ksj) {
            s16x8 pah[2], pal[2], bh[4], bl[4];
            #pragma unroll
            for (int ti = 0; ti < 2; ++ti) {
                int row = rg + ti * 16 + l15;
                int idx = row * 64 + (((ksj * 4 + l4) ^ (row & 7)) * 8);
                pah[ti] = *(const s16x8*)(Ph + idx);
                pal[ti] = *(const s16x8*)(Pl + idx);
            }
            #pragma unroll
            for (int tj = 0; tj < 4; ++tj) {
                int d = dg + tj * 16 + l15;
                int idx = d * 64 + (((ksj * 4 + l4) ^ (d & 7)) * 8);
                bh[tj] = *(const s16x8*)(Vth + idx);
                bl[tj] = *(const s16x8*)(Vtl + idx);
            }
            #pragma unroll
            for (int ti = 0; ti < 2; ++ti)
                #pragma unroll
                for (int tj = 0; tj < 4; ++tj) {
                    acc[ti][tj] = __builtin_amdgcn_mfma_f32_16x16x32_bf16(pah[ti], bh[tj], acc[ti][tj], 0, 0, 0);
                    acc[ti][tj] = __builtin_amdgcn_mfma_f32_16x16x32_bf16(pah[ti], bl[tj], acc[ti][tj], 0, 0, 0);
                    acc[ti][tj] = __builtin_amdgcn_mfma_f32_16x16x32_bf16(pal[ti], bh[tj], acc[ti][tj], 0, 0, 0);
                }
        }
    }

    #pragma unroll
    for (int ti = 0; ti < 2; ++ti)
        #pragma unroll
        for (int r = 0; r < 4; ++r) {
            int row = rg + ti * 16 + l4 * 4 + r;
            #pragma unroll
            for (int tj = 0; tj < 4; ++tj)
                op[(size_t)row * D + dg + tj * 16 + l15] = acc[ti][tj][r];
        }
}

extern "C" void kernel_launch(void* const* d_in, const int* in_sizes, int n_in,
                              void* d_out, int out_size, void* d_ws, size_t ws_size,
                              hipStream_t stream) {
    const float* q = (const float*)d_in[0];
    const float* k = (const float*)d_in[1];
    const float* v = (const float*)d_in[2];
    float* out  = (float*)d_out;                    // [16,2048,128]
    float* attn = out + (size_t)BB * N * D;         // [16,2048,2048]

    const size_t vt_elems = (size_t)BB * D * N;     // 4,194,304
    const bool use_ws = ws_size >= vt_elems * 2 * sizeof(unsigned short);  // 16.78 MB

    if (use_ws) {
        unsigned short* vth = (unsigned short*)d_ws;
        unsigned short* vtl = vth + vt_elems;
        vt_kernel<<<dim3(N / 32, 2, BB), 256, 0, stream>>>(v, vth, vtl);
        qs_kernel<<<(N / 64) * BB, 256, 0, stream>>>(q, k, out);
        fused_kernel<<<(N / 64) * BB, 256, 0, stream>>>(q, k, vth, vtl, attn, out);
    } else {
        zero_kernel<<<1024, 256, 0, stream>>>((float4*)out, BB * N * D / 4);
        qk_kernel<<<dim3(N / 128, N / 128, BB), 256, 0, stream>>>(q, k, attn, out);
        pv_fb_kernel<<<dim3(N / 64, BB), 256, 0, stream>>>(v, attn, out);
    }
}